// Round 2
// baseline (11697.888 us; speedup 1.0000x reference)
//
#include <hip/hip_runtime.h>

#define N_NODES 50000
#define N_EDGES 800000
#define BGRAPH  256
#define DIM     128
#define NLAYER  4
#define EPS     1e-5f

// ---------------- degree / normalization ----------------
__global__ void deg_kernel(const int* __restrict__ dst, int* __restrict__ deg) {
    int e = blockIdx.x * blockDim.x + threadIdx.x;
    if (e < N_EDGES) atomicAdd(&deg[dst[e]], 1);
}

__global__ void dsqrt_kernel(const int* __restrict__ deg, float* __restrict__ dsq) {
    int n = blockIdx.x * blockDim.x + threadIdx.x;
    if (n < N_NODES) {
        float d = (float)(deg[n] < 1 ? 1 : deg[n]);
        dsq[n] = 1.0f / sqrtf(d);
    }
}

// ---------------- atom encoder: H[n,d] = sum_f atom_emb[f, h_idx[n,f], d] ----------------
__global__ void encode_kernel(const int* __restrict__ h_idx,
                              const float* __restrict__ atom_emb,
                              float* __restrict__ H) {
    int n = blockIdx.x;
    int d = threadIdx.x;
    float acc = 0.0f;
#pragma unroll
    for (int f = 0; f < 9; ++f) {
        int idx = h_idx[n * 9 + f];
        acc += atom_emb[(f * 100 + idx) * DIM + d];
    }
    H[n * DIM + d] = acc;
}

// ---------------- edge scatter: A[dst] += X[src] * dsq[src]  (float4 per thread) ----------------
__global__ void scatter_kernel(const int* __restrict__ src, const int* __restrict__ dst,
                               const float* __restrict__ dsq,
                               const float* __restrict__ X, float* __restrict__ A) {
    int idx = blockIdx.x * blockDim.x + threadIdx.x;   // E * 32 threads
    if (idx >= N_EDGES * 32) return;
    int e = idx >> 5;
    int q = (idx & 31) << 2;
    int s = src[e];
    int t = dst[e];
    float w = dsq[s];
    const float4 v = *(const float4*)&X[s * DIM + q];
    atomicAdd(&A[t * DIM + q + 0], v.x * w);
    atomicAdd(&A[t * DIM + q + 1], v.y * w);
    atomicAdd(&A[t * DIM + q + 2], v.z * w);
    atomicAdd(&A[t * DIM + q + 3], v.w * w);
}

// X1 = -dsq[n] * agg   (in place on A)
__global__ void x1_kernel(const float* __restrict__ dsq, float* __restrict__ A) {
    int idx = blockIdx.x * blockDim.x + threadIdx.x;
    if (idx < N_NODES * DIM) {
        int n = idx >> 7;
        A[idx] = -dsq[n] * A[idx];
    }
}

// X2 = -2*dsq[n]*agg - X0   (in place on B)
__global__ void x2_kernel(const float* __restrict__ dsq, const float* __restrict__ H,
                          float* __restrict__ Bb) {
    int idx = blockIdx.x * blockDim.x + threadIdx.x;
    if (idx < N_NODES * DIM) {
        int n = idx >> 7;
        Bb[idx] = -2.0f * dsq[n] * Bb[idx] - H[idx];
    }
}

// ---------------- GEMM: Out = [X0|X1|X2] @ W  (W: 384x128 f32). Out aliases X1 (safe per-block). ----------------
#define GR 4
__global__ void gemm_kernel(const float* __restrict__ X0, const float* __restrict__ X1,
                            const float* __restrict__ X2, const float* __restrict__ W,
                            float* __restrict__ Out) {
    __shared__ float xt[GR][384];
    int c = threadIdx.x;            // 0..127
    int row0 = blockIdx.x * GR;
#pragma unroll
    for (int i = 0; i < GR; ++i) {
        int n = row0 + i;
        xt[i][c]       = X0[n * DIM + c];
        xt[i][128 + c] = X1[n * DIM + c];
        xt[i][256 + c] = X2[n * DIM + c];
    }
    __syncthreads();
    float acc[GR] = {0.f, 0.f, 0.f, 0.f};
    for (int k = 0; k < 384; ++k) {
        float w = W[k * DIM + c];
#pragma unroll
        for (int i = 0; i < GR; ++i) acc[i] += xt[i][k] * w;
    }
#pragma unroll
    for (int i = 0; i < GR; ++i) Out[(row0 + i) * DIM + c] = acc[i];
}

// ---------------- BatchNorm stats: per-channel sum and sumsq ----------------
#define BN_ROWS 128
__global__ void bnstat_kernel(const float* __restrict__ A, float* __restrict__ stats) {
    int d = threadIdx.x;
    int r0 = blockIdx.x * BN_ROWS;
    int rend = r0 + BN_ROWS; if (rend > N_NODES) rend = N_NODES;
    float s = 0.f, s2 = 0.f;
    for (int r = r0; r < rend; ++r) {
        float v = A[r * DIM + d];
        s += v; s2 += v * v;
    }
    atomicAdd(&stats[d], s);
    atomicAdd(&stats[DIM + d], s2);
}

// H += relu( (A - mu) * rsqrt(var+eps) * gamma + beta )
__global__ void bnapply_kernel(const float* __restrict__ A, const float* __restrict__ stats,
                               const float* __restrict__ gamma, const float* __restrict__ beta,
                               float* __restrict__ H) {
    int idx = blockIdx.x * blockDim.x + threadIdx.x;
    if (idx >= N_NODES * DIM) return;
    int d = idx & 127;
    const float invN = 1.0f / (float)N_NODES;
    float mu  = stats[d] * invN;
    float var = stats[DIM + d] * invN - mu * mu;
    float sc  = (1.0f / sqrtf(var + EPS)) * gamma[d];
    float sh  = beta[d] - mu * sc;
    float v = A[idx] * sc + sh;
    H[idx] += fmaxf(v, 0.0f);
}

// ---------------- mean pool (node2graph is sorted -> run-length reduce) ----------------
#define PCHUNK 64
__global__ void pool_kernel(const float* __restrict__ H, const int* __restrict__ n2g,
                            float* __restrict__ sums, float* __restrict__ cnts) {
    int d = threadIdx.x;
    int r0 = blockIdx.x * PCHUNK;
    int rend = r0 + PCHUNK; if (rend > N_NODES) rend = N_NODES;
    if (r0 >= N_NODES) return;
    float acc = 0.0f;
    int cur = n2g[r0];
    int runlen = 0;
    for (int r = r0; r < rend; ++r) {
        int g = n2g[r];
        if (g != cur) {
            atomicAdd(&sums[cur * DIM + d], acc);
            if (d == 0) atomicAdd(&cnts[cur], (float)runlen);
            acc = 0.0f; runlen = 0; cur = g;
        }
        acc += H[r * DIM + d];
        runlen++;
    }
    atomicAdd(&sums[cur * DIM + d], acc);
    if (d == 0) atomicAdd(&cnts[cur], (float)runlen);
}

// ---------------- MLP readout: 128 -> 64 -> 32 -> 128 tasks, output f32 ----------------
__global__ void mlp_kernel(const float* __restrict__ sums, const float* __restrict__ cnts,
                           const float* __restrict__ W0, const float* __restrict__ b0,
                           const float* __restrict__ W1, const float* __restrict__ b1,
                           const float* __restrict__ W2, const float* __restrict__ b2,
                           float* __restrict__ out) {
    __shared__ float hg[DIM];
    __shared__ float y0[64];
    __shared__ float y1[32];
    int g = blockIdx.x;
    int t = threadIdx.x;
    float c = cnts[g]; if (c < 1.0f) c = 1.0f;
    hg[t] = sums[g * DIM + t] / c;
    __syncthreads();
    if (t < 64) {
        float acc = b0[t];
        for (int k = 0; k < 128; ++k) acc += hg[k] * W0[k * 64 + t];
        y0[t] = fmaxf(acc, 0.0f);
    }
    __syncthreads();
    if (t < 32) {
        float acc = b1[t];
        for (int k = 0; k < 64; ++k) acc += y0[k] * W1[k * 32 + t];
        y1[t] = fmaxf(acc, 0.0f);
    }
    __syncthreads();
    {
        float acc = b2[t];
        for (int k = 0; k < 32; ++k) acc += y1[k] * W2[k * 128 + t];
        out[g * DIM + t] = acc;
    }
}

extern "C" void kernel_launch(void* const* d_in, const int* in_sizes, int n_in,
                              void* d_out, int out_size, void* d_ws, size_t ws_size,
                              hipStream_t stream) {
    const int*   h_idx = (const int*)d_in[0];
    // d_in[1] = e_idx (unused by the network)
    const int*   src   = (const int*)d_in[2];
    const int*   dst   = (const int*)d_in[3];
    const int*   n2g   = (const int*)d_in[4];
    const float* atom_emb = (const float*)d_in[5];
    // d_in[6] = bond_emb (unused)
    const float* layer_W  = (const float*)d_in[7];
    const float* gamma    = (const float*)d_in[8];
    const float* beta     = (const float*)d_in[9];
    const float* W0 = (const float*)d_in[10];
    const float* b0 = (const float*)d_in[11];
    const float* W1 = (const float*)d_in[12];
    const float* b1 = (const float*)d_in[13];
    const float* W2 = (const float*)d_in[14];
    const float* b2 = (const float*)d_in[15];

    // workspace layout (~77.3 MB)
    float* H    = (float*)d_ws;                 // N*DIM
    float* A    = H + (size_t)N_NODES * DIM;    // N*DIM
    float* Bb   = A + (size_t)N_NODES * DIM;    // N*DIM
    int*   deg  = (int*)(Bb + (size_t)N_NODES * DIM);
    float* dsq  = (float*)(deg + N_NODES);
    float* stats = dsq + N_NODES;               // 2*DIM
    float* psums = stats + 2 * DIM;             // BGRAPH*DIM
    float* pcnts = psums + BGRAPH * DIM;        // BGRAPH

    const int ND = N_NODES * DIM;

    hipMemsetAsync(deg, 0, N_NODES * sizeof(int), stream);
    deg_kernel<<<(N_EDGES + 255) / 256, 256, 0, stream>>>(dst, deg);
    dsqrt_kernel<<<(N_NODES + 255) / 256, 256, 0, stream>>>(deg, dsq);
    encode_kernel<<<N_NODES, DIM, 0, stream>>>(h_idx, atom_emb, H);

    for (int l = 0; l < NLAYER; ++l) {
        const float* W = layer_W + (size_t)l * 384 * DIM;

        hipMemsetAsync(A, 0, (size_t)ND * sizeof(float), stream);
        scatter_kernel<<<(N_EDGES * 32 + 255) / 256, 256, 0, stream>>>(src, dst, dsq, H, A);
        x1_kernel<<<(ND + 255) / 256, 256, 0, stream>>>(dsq, A);

        hipMemsetAsync(Bb, 0, (size_t)ND * sizeof(float), stream);
        scatter_kernel<<<(N_EDGES * 32 + 255) / 256, 256, 0, stream>>>(src, dst, dsq, A, Bb);
        x2_kernel<<<(ND + 255) / 256, 256, 0, stream>>>(dsq, H, Bb);

        gemm_kernel<<<N_NODES / GR, DIM, 0, stream>>>(H, A, Bb, W, A);

        hipMemsetAsync(stats, 0, 2 * DIM * sizeof(float), stream);
        bnstat_kernel<<<(N_NODES + BN_ROWS - 1) / BN_ROWS, DIM, 0, stream>>>(A, stats);
        bnapply_kernel<<<(ND + 255) / 256, 256, 0, stream>>>(A, stats, gamma + l * DIM, beta + l * DIM, H);
    }

    hipMemsetAsync(psums, 0, (BGRAPH * DIM + BGRAPH) * sizeof(float), stream);
    pool_kernel<<<(N_NODES + PCHUNK - 1) / PCHUNK, DIM, 0, stream>>>(H, n2g, psums, pcnts);
    mlp_kernel<<<BGRAPH, DIM, 0, stream>>>(psums, pcnts, W0, b0, W1, b1, W2, b2, (float*)d_out);
}

// Round 3
// 1686.677 us; speedup vs baseline: 6.9355x; 6.9355x over previous
//
#include <hip/hip_runtime.h>

#define N_NODES 50000
#define N_EDGES 800000
#define BGRAPH  256
#define DIM     128
#define NLAYER  4
#define EPS     1e-5f

// ---------------- degree ----------------
__global__ void deg_kernel(const int* __restrict__ dst, int* __restrict__ deg) {
    int e = blockIdx.x * blockDim.x + threadIdx.x;
    if (e < N_EDGES) atomicAdd(&deg[dst[e]], 1);
}

__global__ void dsqrt_kernel(const int* __restrict__ deg, float* __restrict__ dsq) {
    int n = blockIdx.x * blockDim.x + threadIdx.x;
    if (n < N_NODES) {
        float d = (float)(deg[n] < 1 ? 1 : deg[n]);
        dsq[n] = 1.0f / sqrtf(d);
    }
}

// ---------------- exclusive scan of deg -> row_ptr (single block) ----------------
__global__ void scan_kernel(const int* __restrict__ deg, int* __restrict__ row_ptr) {
    __shared__ int part[1024];
    const int t = threadIdx.x;
    const int CH = (N_NODES + 1023) / 1024;          // 49
    int start = t * CH;
    int end = start + CH; if (end > N_NODES) end = N_NODES;
    int s = 0;
    for (int i = start; i < end; ++i) s += deg[i];
    part[t] = s;
    __syncthreads();
    // inclusive Hillis-Steele scan over 1024 partials
    for (int off = 1; off < 1024; off <<= 1) {
        int v = (t >= off) ? part[t - off] : 0;
        __syncthreads();
        part[t] += v;
        __syncthreads();
    }
    int run = (t == 0) ? 0 : part[t - 1];            // exclusive prefix
    for (int i = start; i < end; ++i) { row_ptr[i] = run; run += deg[i]; }
    if (t == 1023) row_ptr[N_NODES] = part[1023];    // = E
}

__global__ void copy_cursor_kernel(const int* __restrict__ row_ptr, int* __restrict__ cursor) {
    int n = blockIdx.x * blockDim.x + threadIdx.x;
    if (n < N_NODES) cursor[n] = row_ptr[n];
}

// bucket edges by dst: csr_src[slot] = src  (order within row arbitrary)
__global__ void fill_kernel(const int* __restrict__ src, const int* __restrict__ dst,
                            int* __restrict__ cursor, int* __restrict__ csr_src) {
    int e = blockIdx.x * blockDim.x + threadIdx.x;
    if (e < N_EDGES) {
        int t = dst[e];
        int pos = atomicAdd(&cursor[t], 1);
        csr_src[pos] = src[e];
    }
}

// ---------------- atom encoder ----------------
__global__ void encode_kernel(const int* __restrict__ h_idx,
                              const float* __restrict__ atom_emb,
                              float* __restrict__ H) {
    int n = blockIdx.x;
    int d = threadIdx.x;
    float acc = 0.0f;
#pragma unroll
    for (int f = 0; f < 9; ++f) {
        int idx = h_idx[n * 9 + f];
        acc += atom_emb[(f * 100 + idx) * DIM + d];
    }
    H[n * DIM + d] = acc;
}

// ---------------- pull-based prop: Out[n] = alpha*dsq[n]*sum_{s in N(n)} dsq[s]*X[s] + beta*X0[n] ----------------
// 32 lanes per node (float4 each), 8 nodes per 256-thread block. No atomics.
#define PGROUPS 8
__global__ void prop_kernel(const int* __restrict__ row_ptr, const int* __restrict__ csr_src,
                            const float* __restrict__ dsq,
                            const float* __restrict__ X, const float* __restrict__ X0,
                            float alpha, float beta, float* __restrict__ Out) {
    int n = blockIdx.x * PGROUPS + (threadIdx.x >> 5);
    if (n >= N_NODES) return;
    int q = (threadIdx.x & 31) << 2;                 // float offset within row
    int beg = row_ptr[n], endp = row_ptr[n + 1];
    float4 acc = {0.f, 0.f, 0.f, 0.f};
    for (int i = beg; i < endp; ++i) {
        int s = csr_src[i];
        float w = dsq[s];
        const float4 v = *(const float4*)&X[(size_t)s * DIM + q];
        acc.x += v.x * w; acc.y += v.y * w; acc.z += v.z * w; acc.w += v.w * w;
    }
    float a = alpha * dsq[n];
    float4 o;
    if (beta != 0.0f) {
        const float4 x0 = *(const float4*)&X0[(size_t)n * DIM + q];
        o.x = a * acc.x + beta * x0.x;
        o.y = a * acc.y + beta * x0.y;
        o.z = a * acc.z + beta * x0.z;
        o.w = a * acc.w + beta * x0.w;
    } else {
        o.x = a * acc.x; o.y = a * acc.y; o.z = a * acc.z; o.w = a * acc.w;
    }
    *(float4*)&Out[(size_t)n * DIM + q] = o;
}

// ---------------- GEMM: Out = [X0|X1|X2] @ W  (W: 384x128 f32). Out aliases X1 (row-local, safe). ----------------
#define GR 8
__global__ void gemm_kernel(const float* __restrict__ X0, const float* __restrict__ X1,
                            const float* __restrict__ X2, const float* __restrict__ W,
                            float* __restrict__ Out) {
    __shared__ float xt[GR][384];
    int c = threadIdx.x;            // 0..127
    int row0 = blockIdx.x * GR;
#pragma unroll
    for (int i = 0; i < GR; ++i) {
        int n = row0 + i;
        xt[i][c]       = X0[n * DIM + c];
        xt[i][128 + c] = X1[n * DIM + c];
        xt[i][256 + c] = X2[n * DIM + c];
    }
    __syncthreads();
    float acc[GR];
#pragma unroll
    for (int i = 0; i < GR; ++i) acc[i] = 0.f;
    for (int k = 0; k < 384; ++k) {
        float w = W[k * DIM + c];
#pragma unroll
        for (int i = 0; i < GR; ++i) acc[i] += xt[i][k] * w;
    }
#pragma unroll
    for (int i = 0; i < GR; ++i) Out[(row0 + i) * DIM + c] = acc[i];
}

// ---------------- BatchNorm stats ----------------
#define BN_ROWS 128
__global__ void bnstat_kernel(const float* __restrict__ A, float* __restrict__ stats) {
    int d = threadIdx.x;
    int r0 = blockIdx.x * BN_ROWS;
    int rend = r0 + BN_ROWS; if (rend > N_NODES) rend = N_NODES;
    float s = 0.f, s2 = 0.f;
    for (int r = r0; r < rend; ++r) {
        float v = A[r * DIM + d];
        s += v; s2 += v * v;
    }
    atomicAdd(&stats[d], s);
    atomicAdd(&stats[DIM + d], s2);
}

__global__ void bnapply_kernel(const float* __restrict__ A, const float* __restrict__ stats,
                               const float* __restrict__ gamma, const float* __restrict__ beta,
                               float* __restrict__ H) {
    int idx = blockIdx.x * blockDim.x + threadIdx.x;
    if (idx >= N_NODES * DIM) return;
    int d = idx & 127;
    const float invN = 1.0f / (float)N_NODES;
    float mu  = stats[d] * invN;
    float var = stats[DIM + d] * invN - mu * mu;
    float sc  = (1.0f / sqrtf(var + EPS)) * gamma[d];
    float sh  = beta[d] - mu * sc;
    float v = A[idx] * sc + sh;
    H[idx] += fmaxf(v, 0.0f);
}

// ---------------- mean pool (node2graph sorted -> run-length reduce) ----------------
#define PCHUNK 64
__global__ void pool_kernel(const float* __restrict__ H, const int* __restrict__ n2g,
                            float* __restrict__ sums, float* __restrict__ cnts) {
    int d = threadIdx.x;
    int r0 = blockIdx.x * PCHUNK;
    int rend = r0 + PCHUNK; if (rend > N_NODES) rend = N_NODES;
    if (r0 >= N_NODES) return;
    float acc = 0.0f;
    int cur = n2g[r0];
    int runlen = 0;
    for (int r = r0; r < rend; ++r) {
        int g = n2g[r];
        if (g != cur) {
            atomicAdd(&sums[cur * DIM + d], acc);
            if (d == 0) atomicAdd(&cnts[cur], (float)runlen);
            acc = 0.0f; runlen = 0; cur = g;
        }
        acc += H[r * DIM + d];
        runlen++;
    }
    atomicAdd(&sums[cur * DIM + d], acc);
    if (d == 0) atomicAdd(&cnts[cur], (float)runlen);
}

// ---------------- MLP readout ----------------
__global__ void mlp_kernel(const float* __restrict__ sums, const float* __restrict__ cnts,
                           const float* __restrict__ W0, const float* __restrict__ b0,
                           const float* __restrict__ W1, const float* __restrict__ b1,
                           const float* __restrict__ W2, const float* __restrict__ b2,
                           float* __restrict__ out) {
    __shared__ float hg[DIM];
    __shared__ float y0[64];
    __shared__ float y1[32];
    int g = blockIdx.x;
    int t = threadIdx.x;
    float c = cnts[g]; if (c < 1.0f) c = 1.0f;
    hg[t] = sums[g * DIM + t] / c;
    __syncthreads();
    if (t < 64) {
        float acc = b0[t];
        for (int k = 0; k < 128; ++k) acc += hg[k] * W0[k * 64 + t];
        y0[t] = fmaxf(acc, 0.0f);
    }
    __syncthreads();
    if (t < 32) {
        float acc = b1[t];
        for (int k = 0; k < 64; ++k) acc += y0[k] * W1[k * 32 + t];
        y1[t] = fmaxf(acc, 0.0f);
    }
    __syncthreads();
    {
        float acc = b2[t];
        for (int k = 0; k < 32; ++k) acc += y1[k] * W2[k * 128 + t];
        out[g * DIM + t] = acc;
    }
}

extern "C" void kernel_launch(void* const* d_in, const int* in_sizes, int n_in,
                              void* d_out, int out_size, void* d_ws, size_t ws_size,
                              hipStream_t stream) {
    const int*   h_idx = (const int*)d_in[0];
    const int*   src   = (const int*)d_in[2];
    const int*   dst   = (const int*)d_in[3];
    const int*   n2g   = (const int*)d_in[4];
    const float* atom_emb = (const float*)d_in[5];
    const float* layer_W  = (const float*)d_in[7];
    const float* gamma    = (const float*)d_in[8];
    const float* beta     = (const float*)d_in[9];
    const float* W0 = (const float*)d_in[10];
    const float* b0 = (const float*)d_in[11];
    const float* W1 = (const float*)d_in[12];
    const float* b1 = (const float*)d_in[13];
    const float* W2 = (const float*)d_in[14];
    const float* b2 = (const float*)d_in[15];

    // workspace layout (~81 MB)
    float* H    = (float*)d_ws;                       // N*DIM
    float* A    = H + (size_t)N_NODES * DIM;          // N*DIM  (X1, then layer out)
    float* Bb   = A + (size_t)N_NODES * DIM;          // N*DIM  (X2)
    int*   deg  = (int*)(Bb + (size_t)N_NODES * DIM); // N
    float* dsq  = (float*)(deg + N_NODES);            // N
    int*   row_ptr = (int*)(dsq + N_NODES);           // N+1
    int*   cursor  = row_ptr + N_NODES + 1;           // N
    int*   csr_src = cursor + N_NODES;                // E
    float* stats = (float*)(csr_src + N_EDGES);       // 2*DIM
    float* psums = stats + 2 * DIM;                   // BGRAPH*DIM
    float* pcnts = psums + BGRAPH * DIM;              // BGRAPH

    const int ND = N_NODES * DIM;

    // ---- CSR build (once per call) ----
    hipMemsetAsync(deg, 0, N_NODES * sizeof(int), stream);
    deg_kernel<<<(N_EDGES + 255) / 256, 256, 0, stream>>>(dst, deg);
    dsqrt_kernel<<<(N_NODES + 255) / 256, 256, 0, stream>>>(deg, dsq);
    scan_kernel<<<1, 1024, 0, stream>>>(deg, row_ptr);
    copy_cursor_kernel<<<(N_NODES + 255) / 256, 256, 0, stream>>>(row_ptr, cursor);
    fill_kernel<<<(N_EDGES + 255) / 256, 256, 0, stream>>>(src, dst, cursor, csr_src);

    encode_kernel<<<N_NODES, DIM, 0, stream>>>(h_idx, atom_emb, H);

    const int propGrid = (N_NODES + PGROUPS - 1) / PGROUPS;   // 6250
    for (int l = 0; l < NLAYER; ++l) {
        const float* W = layer_W + (size_t)l * 384 * DIM;

        // X1 = -prop(X0)
        prop_kernel<<<propGrid, 256, 0, stream>>>(row_ptr, csr_src, dsq, H, H, -1.0f, 0.0f, A);
        // X2 = -2*prop(X1) - X0
        prop_kernel<<<propGrid, 256, 0, stream>>>(row_ptr, csr_src, dsq, A, H, -2.0f, -1.0f, Bb);

        gemm_kernel<<<N_NODES / GR, DIM, 0, stream>>>(H, A, Bb, W, A);

        hipMemsetAsync(stats, 0, 2 * DIM * sizeof(float), stream);
        bnstat_kernel<<<(N_NODES + BN_ROWS - 1) / BN_ROWS, DIM, 0, stream>>>(A, stats);
        bnapply_kernel<<<(ND + 255) / 256, 256, 0, stream>>>(A, stats, gamma + l * DIM, beta + l * DIM, H);
    }

    hipMemsetAsync(psums, 0, (BGRAPH * DIM + BGRAPH) * sizeof(float), stream);
    pool_kernel<<<(N_NODES + PCHUNK - 1) / PCHUNK, DIM, 0, stream>>>(H, n2g, psums, pcnts);
    mlp_kernel<<<BGRAPH, DIM, 0, stream>>>(psums, pcnts, W0, b0, W1, b1, W2, b2, (float*)d_out);
}

// Round 4
// 1277.642 us; speedup vs baseline: 9.1558x; 1.3201x over previous
//
#include <hip/hip_runtime.h>

#define N_NODES 50000
#define N_EDGES 800000
#define BGRAPH  256
#define DIM     128
#define NLAYER  4
#define EPS     1e-5f

// ---------------- degree ----------------
__global__ void deg_kernel(const int* __restrict__ dst, int* __restrict__ deg) {
    int e = blockIdx.x * blockDim.x + threadIdx.x;
    if (e < N_EDGES) atomicAdd(&deg[dst[e]], 1);
}

__global__ void dsqrt_kernel(const int* __restrict__ deg, float* __restrict__ dsq) {
    int n = blockIdx.x * blockDim.x + threadIdx.x;
    if (n < N_NODES) {
        float d = (float)(deg[n] < 1 ? 1 : deg[n]);
        dsq[n] = 1.0f / sqrtf(d);
    }
}

// ---------------- exclusive scan of deg -> row_ptr (single block) ----------------
__global__ void scan_kernel(const int* __restrict__ deg, int* __restrict__ row_ptr) {
    __shared__ int part[1024];
    const int t = threadIdx.x;
    const int CH = (N_NODES + 1023) / 1024;          // 49
    int start = t * CH;
    int end = start + CH; if (end > N_NODES) end = N_NODES;
    int s = 0;
    for (int i = start; i < end; ++i) s += deg[i];
    part[t] = s;
    __syncthreads();
    for (int off = 1; off < 1024; off <<= 1) {
        int v = (t >= off) ? part[t - off] : 0;
        __syncthreads();
        part[t] += v;
        __syncthreads();
    }
    int run = (t == 0) ? 0 : part[t - 1];
    for (int i = start; i < end; ++i) { row_ptr[i] = run; run += deg[i]; }
    if (t == 1023) row_ptr[N_NODES] = part[1023];
}

__global__ void copy_cursor_kernel(const int* __restrict__ row_ptr, int* __restrict__ cursor) {
    int n = blockIdx.x * blockDim.x + threadIdx.x;
    if (n < N_NODES) cursor[n] = row_ptr[n];
}

__global__ void fill_kernel(const int* __restrict__ src, const int* __restrict__ dst,
                            int* __restrict__ cursor, int* __restrict__ csr_src) {
    int e = blockIdx.x * blockDim.x + threadIdx.x;
    if (e < N_EDGES) {
        int t = dst[e];
        int pos = atomicAdd(&cursor[t], 1);
        csr_src[pos] = src[e];
    }
}

// ---------------- atom encoder ----------------
__global__ void encode_kernel(const int* __restrict__ h_idx,
                              const float* __restrict__ atom_emb,
                              float* __restrict__ H) {
    int n = blockIdx.x;
    int d = threadIdx.x;
    float acc = 0.0f;
#pragma unroll
    for (int f = 0; f < 9; ++f) {
        int idx = h_idx[n * 9 + f];
        acc += atom_emb[(f * 100 + idx) * DIM + d];
    }
    H[n * DIM + d] = acc;
}

// ---------------- pull-based prop ----------------
#define PGROUPS 8
__global__ void prop_kernel(const int* __restrict__ row_ptr, const int* __restrict__ csr_src,
                            const float* __restrict__ dsq,
                            const float* __restrict__ X, const float* __restrict__ X0,
                            float alpha, float beta, float* __restrict__ Out) {
    int n = blockIdx.x * PGROUPS + (threadIdx.x >> 5);
    if (n >= N_NODES) return;
    int q = (threadIdx.x & 31) << 2;
    int beg = row_ptr[n], endp = row_ptr[n + 1];
    float4 acc = {0.f, 0.f, 0.f, 0.f};
    for (int i = beg; i < endp; ++i) {
        int s = csr_src[i];
        float w = dsq[s];
        const float4 v = *(const float4*)&X[(size_t)s * DIM + q];
        acc.x += v.x * w; acc.y += v.y * w; acc.z += v.z * w; acc.w += v.w * w;
    }
    float a = alpha * dsq[n];
    float4 o;
    if (beta != 0.0f) {
        const float4 x0 = *(const float4*)&X0[(size_t)n * DIM + q];
        o.x = a * acc.x + beta * x0.x;
        o.y = a * acc.y + beta * x0.y;
        o.z = a * acc.z + beta * x0.z;
        o.w = a * acc.w + beta * x0.w;
    } else {
        o.x = a * acc.x; o.y = a * acc.y; o.z = a * acc.z; o.w = a * acc.w;
    }
    *(float4*)&Out[(size_t)n * DIM + q] = o;
}

// ---------------- register-tiled GEMM + fused BN stats ----------------
// Out[M,128] = [X0|X1|X2][M,384] @ W[384,128]; per-block tile 64x128, per-thread 8x4.
// Also accumulates per-column sum/sumsq of Out into stats[0..127]/stats[128..255].
#define BM 64
#define BK 64
__global__ __launch_bounds__(256) void gemm_kernel(
        const float* __restrict__ X0, const float* __restrict__ X1,
        const float* __restrict__ X2, const float* __restrict__ W,
        float* __restrict__ Out, float* __restrict__ stats) {
    __shared__ float At[BK][BM];       // 16 KB, [k][m]
    __shared__ float Wt[BK][DIM];      // 32 KB, [k][n]
    const int tid = threadIdx.x;
    const int row0 = blockIdx.x * BM;
    const int nt = tid & 31, mt = tid >> 5;   // compute mapping: 32 x 8
    const int n0 = nt * 4, m0 = mt * 8;
    const int am = tid & 63;                   // staging row within tile
    const int akq0 = tid >> 6;                 // 0..3

    float acc[8][4];
#pragma unroll
    for (int i = 0; i < 8; ++i)
#pragma unroll
        for (int j = 0; j < 4; ++j) acc[i][j] = 0.f;

    const float* bufs[3] = {X0, X1, X2};
    const int arow = row0 + am;
    const bool arow_ok = (arow < N_NODES);

    for (int kc = 0; kc < 6; ++kc) {
        // ---- stage A chunk (transpose to [k][m]) ----
        const float* Xb = bufs[kc >> 1];
        const int col0 = (kc & 1) * 64;
#pragma unroll
        for (int kq = 0; kq < 4; ++kq) {
            int kk = (akq0 + kq * 4);          // 0..15 float4 slots
            float4 v = {0.f, 0.f, 0.f, 0.f};
            if (arow_ok) v = *(const float4*)&Xb[(size_t)arow * DIM + col0 + kk * 4];
            At[kk * 4 + 0][am] = v.x;
            At[kk * 4 + 1][am] = v.y;
            At[kk * 4 + 2][am] = v.z;
            At[kk * 4 + 3][am] = v.w;
        }
        // ---- stage W chunk ----
        const float* Wb = W + (size_t)kc * BK * DIM;
#pragma unroll
        for (int j = 0; j < 8; ++j) {
            int l = tid + j * 256;             // 0..2047 float4 slots
            int k = l >> 5, c4 = (l & 31) * 4;
            *(float4*)&Wt[k][c4] = *(const float4*)&Wb[k * DIM + c4];
        }
        __syncthreads();
        // ---- inner product ----
#pragma unroll 4
        for (int k = 0; k < BK; ++k) {
            float a[8];
            *(float4*)&a[0] = *(const float4*)&At[k][m0];
            *(float4*)&a[4] = *(const float4*)&At[k][m0 + 4];
            float4 w = *(const float4*)&Wt[k][n0];
#pragma unroll
            for (int i = 0; i < 8; ++i) {
                acc[i][0] += a[i] * w.x;
                acc[i][1] += a[i] * w.y;
                acc[i][2] += a[i] * w.z;
                acc[i][3] += a[i] * w.w;
            }
        }
        __syncthreads();
    }

    // ---- write Out (rows < N only; padded rows have acc==0) ----
#pragma unroll
    for (int i = 0; i < 8; ++i) {
        int r = row0 + m0 + i;
        if (r < N_NODES) {
            float4 o = {acc[i][0], acc[i][1], acc[i][2], acc[i][3]};
            *(float4*)&Out[(size_t)r * DIM + n0] = o;
        }
    }

    // ---- fused BN partial stats: column sums over this block's 64 rows ----
    // reduce per-thread (8 rows) then across mt (8 groups) via LDS, then atomics.
    __shared__ float red[8][DIM][2];           // 8 KB (fits in At/Wt space? separate: total 56KB, still <160/2)
#pragma unroll
    for (int j = 0; j < 4; ++j) {
        float s = 0.f, s2 = 0.f;
#pragma unroll
        for (int i = 0; i < 8; ++i) { float v = acc[i][j]; s += v; s2 += v * v; }
        red[mt][n0 + j][0] = s;
        red[mt][n0 + j][1] = s2;
    }
    __syncthreads();
    if (tid < DIM) {
        float s = 0.f, s2 = 0.f;
#pragma unroll
        for (int g = 0; g < 8; ++g) { s += red[g][tid][0]; s2 += red[g][tid][1]; }
        atomicAdd(&stats[tid], s);
        atomicAdd(&stats[DIM + tid], s2);
    }
}

// ---------------- BN apply + relu + residual ----------------
__global__ void bnapply_kernel(const float* __restrict__ A, const float* __restrict__ stats,
                               const float* __restrict__ gamma, const float* __restrict__ beta,
                               float* __restrict__ H) {
    int idx = blockIdx.x * blockDim.x + threadIdx.x;
    if (idx >= N_NODES * DIM) return;
    int d = idx & 127;
    const float invN = 1.0f / (float)N_NODES;
    float mu  = stats[d] * invN;
    float var = stats[DIM + d] * invN - mu * mu;
    float sc  = (1.0f / sqrtf(var + EPS)) * gamma[d];
    float sh  = beta[d] - mu * sc;
    float v = A[idx] * sc + sh;
    H[idx] += fmaxf(v, 0.0f);
}

// ---------------- mean pool ----------------
#define PCHUNK 64
__global__ void pool_kernel(const float* __restrict__ H, const int* __restrict__ n2g,
                            float* __restrict__ sums, float* __restrict__ cnts) {
    int d = threadIdx.x;
    int r0 = blockIdx.x * PCHUNK;
    int rend = r0 + PCHUNK; if (rend > N_NODES) rend = N_NODES;
    if (r0 >= N_NODES) return;
    float acc = 0.0f;
    int cur = n2g[r0];
    int runlen = 0;
    for (int r = r0; r < rend; ++r) {
        int g = n2g[r];
        if (g != cur) {
            atomicAdd(&sums[cur * DIM + d], acc);
            if (d == 0) atomicAdd(&cnts[cur], (float)runlen);
            acc = 0.0f; runlen = 0; cur = g;
        }
        acc += H[r * DIM + d];
        runlen++;
    }
    atomicAdd(&sums[cur * DIM + d], acc);
    if (d == 0) atomicAdd(&cnts[cur], (float)runlen);
}

// ---------------- MLP readout ----------------
__global__ void mlp_kernel(const float* __restrict__ sums, const float* __restrict__ cnts,
                           const float* __restrict__ W0, const float* __restrict__ b0,
                           const float* __restrict__ W1, const float* __restrict__ b1,
                           const float* __restrict__ W2, const float* __restrict__ b2,
                           float* __restrict__ out) {
    __shared__ float hg[DIM];
    __shared__ float y0[64];
    __shared__ float y1[32];
    int g = blockIdx.x;
    int t = threadIdx.x;
    float c = cnts[g]; if (c < 1.0f) c = 1.0f;
    hg[t] = sums[g * DIM + t] / c;
    __syncthreads();
    if (t < 64) {
        float acc = b0[t];
        for (int k = 0; k < 128; ++k) acc += hg[k] * W0[k * 64 + t];
        y0[t] = fmaxf(acc, 0.0f);
    }
    __syncthreads();
    if (t < 32) {
        float acc = b1[t];
        for (int k = 0; k < 64; ++k) acc += y0[k] * W1[k * 32 + t];
        y1[t] = fmaxf(acc, 0.0f);
    }
    __syncthreads();
    {
        float acc = b2[t];
        for (int k = 0; k < 32; ++k) acc += y1[k] * W2[k * 128 + t];
        out[g * DIM + t] = acc;
    }
}

extern "C" void kernel_launch(void* const* d_in, const int* in_sizes, int n_in,
                              void* d_out, int out_size, void* d_ws, size_t ws_size,
                              hipStream_t stream) {
    const int*   h_idx = (const int*)d_in[0];
    const int*   src   = (const int*)d_in[2];
    const int*   dst   = (const int*)d_in[3];
    const int*   n2g   = (const int*)d_in[4];
    const float* atom_emb = (const float*)d_in[5];
    const float* layer_W  = (const float*)d_in[7];
    const float* gamma    = (const float*)d_in[8];
    const float* beta     = (const float*)d_in[9];
    const float* W0 = (const float*)d_in[10];
    const float* b0 = (const float*)d_in[11];
    const float* W1 = (const float*)d_in[12];
    const float* b1 = (const float*)d_in[13];
    const float* W2 = (const float*)d_in[14];
    const float* b2 = (const float*)d_in[15];

    // workspace layout (~81 MB)
    float* H    = (float*)d_ws;                       // N*DIM
    float* A    = H + (size_t)N_NODES * DIM;          // N*DIM  (X1, then layer out)
    float* Bb   = A + (size_t)N_NODES * DIM;          // N*DIM  (X2)
    int*   deg  = (int*)(Bb + (size_t)N_NODES * DIM); // N
    float* dsq  = (float*)(deg + N_NODES);            // N
    int*   row_ptr = (int*)(dsq + N_NODES);           // N+1
    int*   cursor  = row_ptr + N_NODES + 1;           // N
    int*   csr_src = cursor + N_NODES;                // E
    float* stats = (float*)(csr_src + N_EDGES);       // 2*DIM
    float* psums = stats + 2 * DIM;                   // BGRAPH*DIM
    float* pcnts = psums + BGRAPH * DIM;              // BGRAPH

    const int ND = N_NODES * DIM;

    // ---- CSR build ----
    hipMemsetAsync(deg, 0, N_NODES * sizeof(int), stream);
    deg_kernel<<<(N_EDGES + 255) / 256, 256, 0, stream>>>(dst, deg);
    dsqrt_kernel<<<(N_NODES + 255) / 256, 256, 0, stream>>>(deg, dsq);
    scan_kernel<<<1, 1024, 0, stream>>>(deg, row_ptr);
    copy_cursor_kernel<<<(N_NODES + 255) / 256, 256, 0, stream>>>(row_ptr, cursor);
    fill_kernel<<<(N_EDGES + 255) / 256, 256, 0, stream>>>(src, dst, cursor, csr_src);

    encode_kernel<<<N_NODES, DIM, 0, stream>>>(h_idx, atom_emb, H);

    const int propGrid = (N_NODES + PGROUPS - 1) / PGROUPS;
    const int gemmGrid = (N_NODES + BM - 1) / BM;
    for (int l = 0; l < NLAYER; ++l) {
        const float* W = layer_W + (size_t)l * 384 * DIM;

        prop_kernel<<<propGrid, 256, 0, stream>>>(row_ptr, csr_src, dsq, H, H, -1.0f, 0.0f, A);
        prop_kernel<<<propGrid, 256, 0, stream>>>(row_ptr, csr_src, dsq, A, H, -2.0f, -1.0f, Bb);

        hipMemsetAsync(stats, 0, 2 * DIM * sizeof(float), stream);
        gemm_kernel<<<gemmGrid, 256, 0, stream>>>(H, A, Bb, W, A, stats);

        bnapply_kernel<<<(ND + 255) / 256, 256, 0, stream>>>(A, stats, gamma + l * DIM, beta + l * DIM, H);
    }

    hipMemsetAsync(psums, 0, (BGRAPH * DIM + BGRAPH) * sizeof(float), stream);
    pool_kernel<<<(N_NODES + PCHUNK - 1) / PCHUNK, DIM, 0, stream>>>(H, n2g, psums, pcnts);
    mlp_kernel<<<BGRAPH, DIM, 0, stream>>>(psums, pcnts, W0, b0, W1, b1, W2, b2, (float*)d_out);
}

// Round 5
// 937.054 us; speedup vs baseline: 12.4837x; 1.3635x over previous
//
#include <hip/hip_runtime.h>

#define N_NODES 50000
#define N_EDGES 800000
#define BGRAPH  256
#define DIM     128
#define NLAYER  4
#define EPS     1e-5f

typedef _Float16 half4_t __attribute__((ext_vector_type(4)));
typedef _Float16 half8_t __attribute__((ext_vector_type(8)));
typedef float    f32x4   __attribute__((ext_vector_type(4)));

// ---------------- degree ----------------
__global__ void deg_kernel(const int* __restrict__ dst, int* __restrict__ deg) {
    int e = blockIdx.x * blockDim.x + threadIdx.x;
    if (e < N_EDGES) atomicAdd(&deg[dst[e]], 1);
}

__global__ void dsqrt_kernel(const int* __restrict__ deg, float* __restrict__ dsq,
                             float* __restrict__ invd) {
    int n = blockIdx.x * blockDim.x + threadIdx.x;
    if (n < N_NODES) {
        float d = (float)(deg[n] < 1 ? 1 : deg[n]);
        float r = 1.0f / sqrtf(d);
        dsq[n] = r;
        invd[n] = sqrtf(d);      // 1/dsq
    }
}

// ---------------- exclusive scan of deg -> row_ptr (single block) ----------------
__global__ void scan_kernel(const int* __restrict__ deg, int* __restrict__ row_ptr) {
    __shared__ int part[1024];
    const int t = threadIdx.x;
    const int CH = (N_NODES + 1023) / 1024;
    int start = t * CH;
    int end = start + CH; if (end > N_NODES) end = N_NODES;
    int s = 0;
    for (int i = start; i < end; ++i) s += deg[i];
    part[t] = s;
    __syncthreads();
    for (int off = 1; off < 1024; off <<= 1) {
        int v = (t >= off) ? part[t - off] : 0;
        __syncthreads();
        part[t] += v;
        __syncthreads();
    }
    int run = (t == 0) ? 0 : part[t - 1];
    for (int i = start; i < end; ++i) { row_ptr[i] = run; run += deg[i]; }
    if (t == 1023) row_ptr[N_NODES] = part[1023];
}

__global__ void copy_cursor_kernel(const int* __restrict__ row_ptr, int* __restrict__ cursor) {
    int n = blockIdx.x * blockDim.x + threadIdx.x;
    if (n < N_NODES) cursor[n] = row_ptr[n];
}

__global__ void fill_kernel(const int* __restrict__ src, const int* __restrict__ dst,
                            int* __restrict__ cursor, int* __restrict__ csr_src) {
    int e = blockIdx.x * blockDim.x + threadIdx.x;
    if (e < N_EDGES) {
        int t = dst[e];
        int pos = atomicAdd(&cursor[t], 1);
        csr_src[pos] = src[e];
    }
}

// ---------------- W pre-transpose to f16: W16T[l][n][k] = (f16)W[l][k][n] ----------------
__global__ void wcvt_kernel(const float* __restrict__ W, _Float16* __restrict__ W16T) {
    int idx = blockIdx.x * blockDim.x + threadIdx.x;
    if (idx >= NLAYER * 384 * DIM) return;
    int l = idx / (384 * DIM);
    int rem = idx - l * 384 * DIM;
    int k = rem >> 7, n = rem & 127;
    W16T[l * 384 * DIM + n * 384 + k] = (_Float16)W[idx];
}

// ---------------- atom encoder: H f32 + H16s = f16(dsq*H) ----------------
__global__ void encode_kernel(const int* __restrict__ h_idx,
                              const float* __restrict__ atom_emb,
                              const float* __restrict__ dsq,
                              float* __restrict__ H, _Float16* __restrict__ H16s) {
    int n = blockIdx.x;
    int d = threadIdx.x;
    float acc = 0.0f;
#pragma unroll
    for (int f = 0; f < 9; ++f) {
        int idx = h_idx[n * 9 + f];
        acc += atom_emb[(f * 100 + idx) * DIM + d];
    }
    H[n * DIM + d] = acc;
    H16s[n * DIM + d] = (_Float16)(acc * dsq[n]);
}

// ---------------- pull prop on pre-scaled f16: Gout = f16( dsq[n] * (alpha*dsq[n]*sum Gin[s] + beta*X0[n]) )
#define PGROUPS 8
__global__ void prop_kernel(const int* __restrict__ row_ptr, const int* __restrict__ csr_src,
                            const float* __restrict__ dsq,
                            const _Float16* __restrict__ Gin, const float* __restrict__ X0,
                            float alpha, float beta, _Float16* __restrict__ Gout) {
    int n = blockIdx.x * PGROUPS + (threadIdx.x >> 5);
    if (n >= N_NODES) return;
    int q = (threadIdx.x & 31) << 2;                 // f16 offset within row
    int beg = row_ptr[n], endp = row_ptr[n + 1];
    float4 acc = {0.f, 0.f, 0.f, 0.f};
    int i = beg;
    for (; i + 4 <= endp; i += 4) {
        int s0 = csr_src[i], s1 = csr_src[i + 1], s2 = csr_src[i + 2], s3 = csr_src[i + 3];
        half4_t r0 = *(const half4_t*)&Gin[(size_t)s0 * DIM + q];
        half4_t r1 = *(const half4_t*)&Gin[(size_t)s1 * DIM + q];
        half4_t r2 = *(const half4_t*)&Gin[(size_t)s2 * DIM + q];
        half4_t r3 = *(const half4_t*)&Gin[(size_t)s3 * DIM + q];
        acc.x += (float)r0[0] + (float)r1[0] + (float)r2[0] + (float)r3[0];
        acc.y += (float)r0[1] + (float)r1[1] + (float)r2[1] + (float)r3[1];
        acc.z += (float)r0[2] + (float)r1[2] + (float)r2[2] + (float)r3[2];
        acc.w += (float)r0[3] + (float)r1[3] + (float)r2[3] + (float)r3[3];
    }
    for (; i < endp; ++i) {
        int s = csr_src[i];
        half4_t r = *(const half4_t*)&Gin[(size_t)s * DIM + q];
        acc.x += (float)r[0]; acc.y += (float)r[1]; acc.z += (float)r[2]; acc.w += (float)r[3];
    }
    float g = dsq[n];
    float a = alpha * g;
    float4 o;
    if (beta != 0.0f) {
        const float4 x0 = *(const float4*)&X0[(size_t)n * DIM + q];
        o.x = a * acc.x + beta * x0.x;
        o.y = a * acc.y + beta * x0.y;
        o.z = a * acc.z + beta * x0.z;
        o.w = a * acc.w + beta * x0.w;
    } else {
        o.x = a * acc.x; o.y = a * acc.y; o.z = a * acc.z; o.w = a * acc.w;
    }
    half4_t out;
    out[0] = (_Float16)(o.x * g); out[1] = (_Float16)(o.y * g);
    out[2] = (_Float16)(o.z * g); out[3] = (_Float16)(o.w * g);
    *(half4_t*)&Gout[(size_t)n * DIM + q] = out;
}

// ---------------- MFMA GEMM: Out16 = [X0|X1|X2] @ W  with per-row unscale, fused BN stats ----------------
// block = 256 (4 waves), tile M=64 (16 rows/wave) x N=128 (8 mfma tiles), K=384 (12 x 32).
// A-frag: lane holds A[m=lane&15][k=quad*8+j]; B-frag: B[n=lane&15][k=quad*8+j] from W16T[n][k].
// C/D: col=lane&15, row=quad*4+reg  (verified layout).
__global__ __launch_bounds__(256) void gemm_kernel(
        const _Float16* __restrict__ X0s, const _Float16* __restrict__ X1s,
        const _Float16* __restrict__ X2s, const float* __restrict__ invd,
        const _Float16* __restrict__ W16T,
        _Float16* __restrict__ Out16, float* __restrict__ stats) {
    const int tid  = threadIdx.x;
    const int wave = tid >> 6;
    const int lane = tid & 63;
    const int quad = lane >> 4;
    const int l15  = lane & 15;
    const int row0 = blockIdx.x * 64 + wave * 16;
    const int arow = row0 + l15;
    const int arow_c = (arow < N_NODES) ? arow : (N_NODES - 1);   // clamp load, zero via rs
    const float rs = (arow < N_NODES) ? invd[arow] : 0.0f;
    const _Float16 rsh = (_Float16)rs;

    f32x4 acc[8];
#pragma unroll
    for (int t = 0; t < 8; ++t) acc[t] = (f32x4){0.f, 0.f, 0.f, 0.f};

    const _Float16* bufs[3] = {X0s, X1s, X2s};

    for (int kb = 0; kb < 12; ++kb) {
        const _Float16* Xb = bufs[kb >> 2];
        const int c0 = ((kb & 3) << 5) + (quad << 3);
        half8_t a = *(const half8_t*)&Xb[(size_t)arow_c * DIM + c0];
#pragma unroll
        for (int j = 0; j < 8; ++j) a[j] = a[j] * rsh;      // unscale (or zero OOB)
        const _Float16* Wk = W16T + (kb << 5) + (quad << 3);
#pragma unroll
        for (int t = 0; t < 8; ++t) {
            half8_t b = *(const half8_t*)&Wk[(size_t)((t << 4) + l15) * 384];
            acc[t] = __builtin_amdgcn_mfma_f32_16x16x32_f16(a, b, acc[t], 0, 0, 0);
        }
    }

    // ---- store + fused BN stats ----
    __shared__ float sred[4][DIM];
    __shared__ float s2red[4][DIM];
#pragma unroll
    for (int t = 0; t < 8; ++t) {
        const int c = (t << 4) + l15;
        float s = 0.f, s2 = 0.f;
#pragma unroll
        for (int reg = 0; reg < 4; ++reg) {
            float v = acc[t][reg];
            s += v; s2 += v * v;
            int r = row0 + (quad << 2) + reg;
            if (r < N_NODES) Out16[(size_t)r * DIM + c] = (_Float16)v;
        }
        s  += __shfl_xor(s, 16);  s  += __shfl_xor(s, 32);
        s2 += __shfl_xor(s2, 16); s2 += __shfl_xor(s2, 32);
        if (quad == 0) { sred[wave][c] = s; s2red[wave][c] = s2; }
    }
    __syncthreads();
    if (tid < DIM) {
        float s = 0.f, s2 = 0.f;
#pragma unroll
        for (int w = 0; w < 4; ++w) { s += sred[w][tid]; s2 += s2red[w][tid]; }
        atomicAdd(&stats[tid], s);
        atomicAdd(&stats[DIM + tid], s2);
    }
}

// ---------------- BN apply + relu + residual; refresh H16s ----------------
__global__ void bnapply_kernel(const _Float16* __restrict__ Out16, const float* __restrict__ stats,
                               const float* __restrict__ gamma, const float* __restrict__ beta,
                               const float* __restrict__ dsq,
                               float* __restrict__ H, _Float16* __restrict__ H16s) {
    int idx = blockIdx.x * blockDim.x + threadIdx.x;
    if (idx >= N_NODES * DIM) return;
    int d = idx & 127;
    int n = idx >> 7;
    const float invN = 1.0f / (float)N_NODES;
    float mu  = stats[d] * invN;
    float var = stats[DIM + d] * invN - mu * mu;
    float sc  = (1.0f / sqrtf(var + EPS)) * gamma[d];
    float sh  = beta[d] - mu * sc;
    float v = (float)Out16[idx] * sc + sh;
    float h = H[idx] + fmaxf(v, 0.0f);
    H[idx] = h;
    H16s[idx] = (_Float16)(h * dsq[n]);
}

// ---------------- mean pool (node2graph sorted -> run-length reduce) ----------------
#define PCHUNK 64
__global__ void pool_kernel(const float* __restrict__ H, const int* __restrict__ n2g,
                            float* __restrict__ sums, float* __restrict__ cnts) {
    int d = threadIdx.x;
    int r0 = blockIdx.x * PCHUNK;
    int rend = r0 + PCHUNK; if (rend > N_NODES) rend = N_NODES;
    if (r0 >= N_NODES) return;
    float acc = 0.0f;
    int cur = n2g[r0];
    int runlen = 0;
    for (int r = r0; r < rend; ++r) {
        int g = n2g[r];
        if (g != cur) {
            atomicAdd(&sums[cur * DIM + d], acc);
            if (d == 0) atomicAdd(&cnts[cur], (float)runlen);
            acc = 0.0f; runlen = 0; cur = g;
        }
        acc += H[r * DIM + d];
        runlen++;
    }
    atomicAdd(&sums[cur * DIM + d], acc);
    if (d == 0) atomicAdd(&cnts[cur], (float)runlen);
}

// ---------------- MLP readout ----------------
__global__ void mlp_kernel(const float* __restrict__ sums, const float* __restrict__ cnts,
                           const float* __restrict__ W0, const float* __restrict__ b0,
                           const float* __restrict__ W1, const float* __restrict__ b1,
                           const float* __restrict__ W2, const float* __restrict__ b2,
                           float* __restrict__ out) {
    __shared__ float hg[DIM];
    __shared__ float y0[64];
    __shared__ float y1[32];
    int g = blockIdx.x;
    int t = threadIdx.x;
    float c = cnts[g]; if (c < 1.0f) c = 1.0f;
    hg[t] = sums[g * DIM + t] / c;
    __syncthreads();
    if (t < 64) {
        float acc = b0[t];
        for (int k = 0; k < 128; ++k) acc += hg[k] * W0[k * 64 + t];
        y0[t] = fmaxf(acc, 0.0f);
    }
    __syncthreads();
    if (t < 32) {
        float acc = b1[t];
        for (int k = 0; k < 64; ++k) acc += y0[k] * W1[k * 32 + t];
        y1[t] = fmaxf(acc, 0.0f);
    }
    __syncthreads();
    {
        float acc = b2[t];
        for (int k = 0; k < 32; ++k) acc += y1[k] * W2[k * 128 + t];
        out[g * DIM + t] = acc;
    }
}

extern "C" void kernel_launch(void* const* d_in, const int* in_sizes, int n_in,
                              void* d_out, int out_size, void* d_ws, size_t ws_size,
                              hipStream_t stream) {
    const int*   h_idx = (const int*)d_in[0];
    const int*   src   = (const int*)d_in[2];
    const int*   dst   = (const int*)d_in[3];
    const int*   n2g   = (const int*)d_in[4];
    const float* atom_emb = (const float*)d_in[5];
    const float* layer_W  = (const float*)d_in[7];
    const float* gamma    = (const float*)d_in[8];
    const float* beta     = (const float*)d_in[9];
    const float* W0 = (const float*)d_in[10];
    const float* b0 = (const float*)d_in[11];
    const float* W1 = (const float*)d_in[12];
    const float* b1 = (const float*)d_in[13];
    const float* W2 = (const float*)d_in[14];
    const float* b2 = (const float*)d_in[15];

    const size_t ND = (size_t)N_NODES * DIM;

    // workspace layout (~81.5 MB)
    float*    H    = (float*)d_ws;                     // ND f32
    _Float16* H16s = (_Float16*)(H + ND);              // ND f16 (dsq-scaled X0)
    _Float16* A16s = H16s + ND;                        // ND f16 (dsq-scaled X1)
    _Float16* B16s = A16s + ND;                        // ND f16 (dsq-scaled X2)
    _Float16* Out16 = B16s + ND;                       // ND f16 (gemm out)
    _Float16* W16T = Out16 + ND;                       // 4*384*128 f16
    float* dsq  = (float*)(W16T + NLAYER * 384 * DIM); // N
    float* invd = dsq + N_NODES;                       // N
    int*   deg  = (int*)(invd + N_NODES);              // N
    int*   row_ptr = deg + N_NODES;                    // N+1
    int*   cursor  = row_ptr + N_NODES + 1;            // N
    int*   csr_src = cursor + N_NODES;                 // E
    float* stats = (float*)(csr_src + N_EDGES);        // 2*DIM
    float* psums = stats + 2 * DIM;                    // BGRAPH*DIM
    float* pcnts = psums + BGRAPH * DIM;               // BGRAPH

    // ---- CSR build + weight convert ----
    hipMemsetAsync(deg, 0, N_NODES * sizeof(int), stream);
    deg_kernel<<<(N_EDGES + 255) / 256, 256, 0, stream>>>(dst, deg);
    dsqrt_kernel<<<(N_NODES + 255) / 256, 256, 0, stream>>>(deg, dsq, invd);
    scan_kernel<<<1, 1024, 0, stream>>>(deg, row_ptr);
    copy_cursor_kernel<<<(N_NODES + 255) / 256, 256, 0, stream>>>(row_ptr, cursor);
    fill_kernel<<<(N_EDGES + 255) / 256, 256, 0, stream>>>(src, dst, cursor, csr_src);
    wcvt_kernel<<<(NLAYER * 384 * DIM + 255) / 256, 256, 0, stream>>>(layer_W, W16T);

    encode_kernel<<<N_NODES, DIM, 0, stream>>>(h_idx, atom_emb, dsq, H, H16s);

    const int propGrid = (N_NODES + PGROUPS - 1) / PGROUPS;
    const int gemmGrid = (N_NODES + 63) / 64;
    for (int l = 0; l < NLAYER; ++l) {
        // X1s = scaled(-prop(X0));  X2s = scaled(-2*prop(X1) - X0)
        prop_kernel<<<propGrid, 256, 0, stream>>>(row_ptr, csr_src, dsq, H16s, H, -1.0f, 0.0f, A16s);
        prop_kernel<<<propGrid, 256, 0, stream>>>(row_ptr, csr_src, dsq, A16s, H, -2.0f, -1.0f, B16s);

        hipMemsetAsync(stats, 0, 2 * DIM * sizeof(float), stream);
        gemm_kernel<<<gemmGrid, 256, 0, stream>>>(H16s, A16s, B16s, invd,
                                                  W16T + (size_t)l * 384 * DIM, Out16, stats);

        bnapply_kernel<<<((int)ND + 255) / 256, 256, 0, stream>>>(Out16, stats,
                                                  gamma + l * DIM, beta + l * DIM, dsq, H, H16s);
    }

    hipMemsetAsync(psums, 0, (BGRAPH * DIM + BGRAPH) * sizeof(float), stream);
    pool_kernel<<<(N_NODES + PCHUNK - 1) / PCHUNK, DIM, 0, stream>>>(H, n2g, psums, pcnts);
    mlp_kernel<<<BGRAPH, DIM, 0, stream>>>(psums, pcnts, W0, b0, W1, b1, W2, b2, (float*)d_out);
}

// Round 6
// 846.027 us; speedup vs baseline: 13.8268x; 1.1076x over previous
//
#include <hip/hip_runtime.h>

#define N_NODES 50000
#define N_EDGES 800000
#define BGRAPH  256
#define DIM     128
#define NLAYER  4
#define EPS     1e-5f
#define NPART   ((N_NODES + 255) / 256)   // 196 scan partials

typedef _Float16 half8_t __attribute__((ext_vector_type(8)));
typedef float    f32x4   __attribute__((ext_vector_type(4)));

// ---------------- degree ----------------
__global__ void deg_kernel(const int* __restrict__ dst, int* __restrict__ deg) {
    int e = blockIdx.x * blockDim.x + threadIdx.x;
    if (e < N_EDGES) atomicAdd(&deg[dst[e]], 1);
}

// ---------------- hierarchical scan: deg -> row_ptr (+cursor, dsq, invd) ----------------
__global__ void scan1_kernel(const int* __restrict__ deg, int* __restrict__ part) {
    __shared__ int lds[256];
    int t = threadIdx.x;
    int i = blockIdx.x * 256 + t;
    lds[t] = (i < N_NODES) ? deg[i] : 0;
    __syncthreads();
    for (int off = 128; off > 0; off >>= 1) {
        if (t < off) lds[t] += lds[t + off];
        __syncthreads();
    }
    if (t == 0) part[blockIdx.x] = lds[0];
}

__global__ void scan2_kernel(int* __restrict__ part) {
    __shared__ int lds[256];
    int t = threadIdx.x;
    int v = (t < NPART) ? part[t] : 0;
    lds[t] = v;
    __syncthreads();
    for (int off = 1; off < 256; off <<= 1) {
        int u = (t >= off) ? lds[t - off] : 0;
        __syncthreads();
        lds[t] += u;
        __syncthreads();
    }
    if (t < NPART) part[t] = lds[t] - v;    // exclusive
}

__global__ void scan3_kernel(const int* __restrict__ deg, const int* __restrict__ part,
                             int* __restrict__ row_ptr, int* __restrict__ cursor,
                             float* __restrict__ dsq, float* __restrict__ invd) {
    __shared__ int lds[256];
    int t = threadIdx.x;
    int i = blockIdx.x * 256 + t;
    int v = (i < N_NODES) ? deg[i] : 0;
    lds[t] = v;
    __syncthreads();
    for (int off = 1; off < 256; off <<= 1) {
        int u = (t >= off) ? lds[t - off] : 0;
        __syncthreads();
        lds[t] += u;
        __syncthreads();
    }
    int excl = lds[t] - v + part[blockIdx.x];
    if (i < N_NODES) {
        row_ptr[i] = excl;
        cursor[i] = excl;
        float d = (float)(v < 1 ? 1 : v);
        dsq[i] = 1.0f / sqrtf(d);
        invd[i] = sqrtf(d);
        if (i == N_NODES - 1) row_ptr[N_NODES] = excl + v;
    }
}

__global__ void fill_kernel(const int* __restrict__ src, const int* __restrict__ dst,
                            int* __restrict__ cursor, int* __restrict__ csr_src) {
    int e = blockIdx.x * blockDim.x + threadIdx.x;
    if (e < N_EDGES) {
        int t = dst[e];
        int pos = atomicAdd(&cursor[t], 1);
        csr_src[pos] = src[e];
    }
}

// ---------------- W pre-transpose to f16: W16T[l][n][k] = (f16)W[l][k][n] ----------------
__global__ void wcvt_kernel(const float* __restrict__ W, _Float16* __restrict__ W16T) {
    int idx = blockIdx.x * blockDim.x + threadIdx.x;
    if (idx >= NLAYER * 384 * DIM) return;
    int l = idx / (384 * DIM);
    int rem = idx - l * 384 * DIM;
    int k = rem >> 7, n = rem & 127;
    W16T[l * 384 * DIM + n * 384 + k] = (_Float16)W[idx];
}

// ---------------- atom encoder: H f32 + H16s = f16(dsq*H) ----------------
__global__ void encode_kernel(const int* __restrict__ h_idx,
                              const float* __restrict__ atom_emb,
                              const float* __restrict__ dsq,
                              float* __restrict__ H, _Float16* __restrict__ H16s) {
    int n = blockIdx.x;
    int d = threadIdx.x;
    float acc = 0.0f;
#pragma unroll
    for (int f = 0; f < 9; ++f) {
        int idx = h_idx[n * 9 + f];
        acc += atom_emb[(f * 100 + idx) * DIM + d];
    }
    H[n * DIM + d] = acc;
    H16s[n * DIM + d] = (_Float16)(acc * dsq[n]);
}

// ---------------- pull prop: 16 lanes/node, half8 (16 B) per lane ----------------
#define PGROUPS 16
__global__ void prop_kernel(const int* __restrict__ row_ptr, const int* __restrict__ csr_src,
                            const float* __restrict__ dsq,
                            const _Float16* __restrict__ Gin, const float* __restrict__ X0,
                            float alpha, float beta, _Float16* __restrict__ Gout) {
    int n = blockIdx.x * PGROUPS + (threadIdx.x >> 4);
    if (n >= N_NODES) return;
    int q = (threadIdx.x & 15) << 3;                 // f16 offset within row
    int beg = row_ptr[n], endp = row_ptr[n + 1];
    float acc[8];
#pragma unroll
    for (int j = 0; j < 8; ++j) acc[j] = 0.f;
    int i = beg;
    for (; i + 4 <= endp; i += 4) {
        int s0 = csr_src[i], s1 = csr_src[i + 1], s2 = csr_src[i + 2], s3 = csr_src[i + 3];
        half8_t r0 = *(const half8_t*)&Gin[(size_t)s0 * DIM + q];
        half8_t r1 = *(const half8_t*)&Gin[(size_t)s1 * DIM + q];
        half8_t r2 = *(const half8_t*)&Gin[(size_t)s2 * DIM + q];
        half8_t r3 = *(const half8_t*)&Gin[(size_t)s3 * DIM + q];
#pragma unroll
        for (int j = 0; j < 8; ++j)
            acc[j] += (float)r0[j] + (float)r1[j] + (float)r2[j] + (float)r3[j];
    }
    for (; i < endp; ++i) {
        int s = csr_src[i];
        half8_t r = *(const half8_t*)&Gin[(size_t)s * DIM + q];
#pragma unroll
        for (int j = 0; j < 8; ++j) acc[j] += (float)r[j];
    }
    float g = dsq[n];
    float a = alpha * g;
    half8_t out;
    if (beta != 0.0f) {
        const float* x0p = &X0[(size_t)n * DIM + q];
        float4 xa = *(const float4*)x0p;
        float4 xb = *(const float4*)(x0p + 4);
        float x0v[8] = {xa.x, xa.y, xa.z, xa.w, xb.x, xb.y, xb.z, xb.w};
#pragma unroll
        for (int j = 0; j < 8; ++j)
            out[j] = (_Float16)((a * acc[j] + beta * x0v[j]) * g);
    } else {
#pragma unroll
        for (int j = 0; j < 8; ++j)
            out[j] = (_Float16)(a * acc[j] * g);
    }
    *(half8_t*)&Gout[(size_t)n * DIM + q] = out;
}

// ---------------- MFMA GEMM + fused BN stats ----------------
__global__ __launch_bounds__(256) void gemm_kernel(
        const _Float16* __restrict__ X0s, const _Float16* __restrict__ X1s,
        const _Float16* __restrict__ X2s, const float* __restrict__ invd,
        const _Float16* __restrict__ W16T,
        _Float16* __restrict__ Out16, float* __restrict__ stats) {
    const int tid  = threadIdx.x;
    const int wave = tid >> 6;
    const int lane = tid & 63;
    const int quad = lane >> 4;
    const int l15  = lane & 15;
    const int row0 = blockIdx.x * 64 + wave * 16;
    const int arow = row0 + l15;
    const int arow_c = (arow < N_NODES) ? arow : (N_NODES - 1);
    const float rs = (arow < N_NODES) ? invd[arow] : 0.0f;
    const _Float16 rsh = (_Float16)rs;

    f32x4 acc[8];
#pragma unroll
    for (int t = 0; t < 8; ++t) acc[t] = (f32x4){0.f, 0.f, 0.f, 0.f};

    const _Float16* bufs[3] = {X0s, X1s, X2s};

    for (int kb = 0; kb < 12; ++kb) {
        const _Float16* Xb = bufs[kb >> 2];
        const int c0 = ((kb & 3) << 5) + (quad << 3);
        half8_t a = *(const half8_t*)&Xb[(size_t)arow_c * DIM + c0];
#pragma unroll
        for (int j = 0; j < 8; ++j) a[j] = a[j] * rsh;
        const _Float16* Wk = W16T + (kb << 5) + (quad << 3);
#pragma unroll
        for (int t = 0; t < 8; ++t) {
            half8_t b = *(const half8_t*)&Wk[(size_t)((t << 4) + l15) * 384];
            acc[t] = __builtin_amdgcn_mfma_f32_16x16x32_f16(a, b, acc[t], 0, 0, 0);
        }
    }

    __shared__ float sred[4][DIM];
    __shared__ float s2red[4][DIM];
#pragma unroll
    for (int t = 0; t < 8; ++t) {
        const int c = (t << 4) + l15;
        float s = 0.f, s2 = 0.f;
#pragma unroll
        for (int reg = 0; reg < 4; ++reg) {
            float v = acc[t][reg];
            s += v; s2 += v * v;
            int r = row0 + (quad << 2) + reg;
            if (r < N_NODES) Out16[(size_t)r * DIM + c] = (_Float16)v;
        }
        s  += __shfl_xor(s, 16);  s  += __shfl_xor(s, 32);
        s2 += __shfl_xor(s2, 16); s2 += __shfl_xor(s2, 32);
        if (quad == 0) { sred[wave][c] = s; s2red[wave][c] = s2; }
    }
    __syncthreads();
    if (tid < DIM) {
        float s = 0.f, s2 = 0.f;
#pragma unroll
        for (int w = 0; w < 4; ++w) { s += sred[w][tid]; s2 += s2red[w][tid]; }
        atomicAdd(&stats[tid], s);
        atomicAdd(&stats[DIM + tid], s2);
    }
}

// ---------------- BN apply + relu + residual; refresh H16s ----------------
__global__ void bnapply_kernel(const _Float16* __restrict__ Out16, const float* __restrict__ stats,
                               const float* __restrict__ gamma, const float* __restrict__ beta,
                               const float* __restrict__ dsq,
                               float* __restrict__ H, _Float16* __restrict__ H16s) {
    int idx = blockIdx.x * blockDim.x + threadIdx.x;
    if (idx >= N_NODES * DIM) return;
    int d = idx & 127;
    int n = idx >> 7;
    const float invN = 1.0f / (float)N_NODES;
    float mu  = stats[d] * invN;
    float var = stats[DIM + d] * invN - mu * mu;
    float sc  = (1.0f / sqrtf(var + EPS)) * gamma[d];
    float sh  = beta[d] - mu * sc;
    float v = (float)Out16[idx] * sc + sh;
    float h = H[idx] + fmaxf(v, 0.0f);
    H[idx] = h;
    H16s[idx] = (_Float16)(h * dsq[n]);
}

// ---------------- mean pool ----------------
#define PCHUNK 64
__global__ void pool_kernel(const float* __restrict__ H, const int* __restrict__ n2g,
                            float* __restrict__ sums, float* __restrict__ cnts) {
    int d = threadIdx.x;
    int r0 = blockIdx.x * PCHUNK;
    int rend = r0 + PCHUNK; if (rend > N_NODES) rend = N_NODES;
    if (r0 >= N_NODES) return;
    float acc = 0.0f;
    int cur = n2g[r0];
    int runlen = 0;
    for (int r = r0; r < rend; ++r) {
        int g = n2g[r];
        if (g != cur) {
            atomicAdd(&sums[cur * DIM + d], acc);
            if (d == 0) atomicAdd(&cnts[cur], (float)runlen);
            acc = 0.0f; runlen = 0; cur = g;
        }
        acc += H[r * DIM + d];
        runlen++;
    }
    atomicAdd(&sums[cur * DIM + d], acc);
    if (d == 0) atomicAdd(&cnts[cur], (float)runlen);
}

// ---------------- MLP readout ----------------
__global__ void mlp_kernel(const float* __restrict__ sums, const float* __restrict__ cnts,
                           const float* __restrict__ W0, const float* __restrict__ b0,
                           const float* __restrict__ W1, const float* __restrict__ b1,
                           const float* __restrict__ W2, const float* __restrict__ b2,
                           float* __restrict__ out) {
    __shared__ float hg[DIM];
    __shared__ float y0[64];
    __shared__ float y1[32];
    int g = blockIdx.x;
    int t = threadIdx.x;
    float c = cnts[g]; if (c < 1.0f) c = 1.0f;
    hg[t] = sums[g * DIM + t] / c;
    __syncthreads();
    if (t < 64) {
        float acc = b0[t];
        for (int k = 0; k < 128; ++k) acc += hg[k] * W0[k * 64 + t];
        y0[t] = fmaxf(acc, 0.0f);
    }
    __syncthreads();
    if (t < 32) {
        float acc = b1[t];
        for (int k = 0; k < 64; ++k) acc += y0[k] * W1[k * 32 + t];
        y1[t] = fmaxf(acc, 0.0f);
    }
    __syncthreads();
    {
        float acc = b2[t];
        for (int k = 0; k < 32; ++k) acc += y1[k] * W2[k * 128 + t];
        out[g * DIM + t] = acc;
    }
}

extern "C" void kernel_launch(void* const* d_in, const int* in_sizes, int n_in,
                              void* d_out, int out_size, void* d_ws, size_t ws_size,
                              hipStream_t stream) {
    const int*   h_idx = (const int*)d_in[0];
    const int*   src   = (const int*)d_in[2];
    const int*   dst   = (const int*)d_in[3];
    const int*   n2g   = (const int*)d_in[4];
    const float* atom_emb = (const float*)d_in[5];
    const float* layer_W  = (const float*)d_in[7];
    const float* gamma    = (const float*)d_in[8];
    const float* beta     = (const float*)d_in[9];
    const float* W0 = (const float*)d_in[10];
    const float* b0 = (const float*)d_in[11];
    const float* W1 = (const float*)d_in[12];
    const float* b1 = (const float*)d_in[13];
    const float* W2 = (const float*)d_in[14];
    const float* b2 = (const float*)d_in[15];

    const size_t ND = (size_t)N_NODES * DIM;

    // workspace layout (~82 MB)
    float*    H    = (float*)d_ws;                     // ND f32
    _Float16* H16s = (_Float16*)(H + ND);              // ND f16 (dsq-scaled X0)
    _Float16* A16s = H16s + ND;                        // ND f16 (dsq-scaled X1)
    _Float16* B16s = A16s + ND;                        // ND f16 (dsq-scaled X2)
    _Float16* Out16 = B16s + ND;                       // ND f16 (gemm out)
    _Float16* W16T = Out16 + ND;                       // 4*384*128 f16
    float* dsq  = (float*)(W16T + NLAYER * 384 * DIM); // N
    float* invd = dsq + N_NODES;                       // N
    int*   deg  = (int*)(invd + N_NODES);              // N
    int*   row_ptr = deg + N_NODES;                    // N+1
    int*   cursor  = row_ptr + N_NODES + 1;            // N
    int*   part    = cursor + N_NODES;                 // NPART
    int*   csr_src = part + 256;                       // E
    float* stats = (float*)(csr_src + N_EDGES);        // 2*DIM
    float* psums = stats + 2 * DIM;                    // BGRAPH*DIM
    float* pcnts = psums + BGRAPH * DIM;               // BGRAPH

    // ---- CSR build + weight convert ----
    hipMemsetAsync(deg, 0, N_NODES * sizeof(int), stream);
    deg_kernel<<<(N_EDGES + 255) / 256, 256, 0, stream>>>(dst, deg);
    scan1_kernel<<<NPART, 256, 0, stream>>>(deg, part);
    scan2_kernel<<<1, 256, 0, stream>>>(part);
    scan3_kernel<<<NPART, 256, 0, stream>>>(deg, part, row_ptr, cursor, dsq, invd);
    fill_kernel<<<(N_EDGES + 255) / 256, 256, 0, stream>>>(src, dst, cursor, csr_src);
    wcvt_kernel<<<(NLAYER * 384 * DIM + 255) / 256, 256, 0, stream>>>(layer_W, W16T);

    encode_kernel<<<N_NODES, DIM, 0, stream>>>(h_idx, atom_emb, dsq, H, H16s);

    const int propGrid = (N_NODES + PGROUPS - 1) / PGROUPS;
    const int gemmGrid = (N_NODES + 63) / 64;
    for (int l = 0; l < NLAYER; ++l) {
        prop_kernel<<<propGrid, 256, 0, stream>>>(row_ptr, csr_src, dsq, H16s, H, -1.0f, 0.0f, A16s);
        prop_kernel<<<propGrid, 256, 0, stream>>>(row_ptr, csr_src, dsq, A16s, H, -2.0f, -1.0f, B16s);

        hipMemsetAsync(stats, 0, 2 * DIM * sizeof(float), stream);
        gemm_kernel<<<gemmGrid, 256, 0, stream>>>(H16s, A16s, B16s, invd,
                                                  W16T + (size_t)l * 384 * DIM, Out16, stats);

        bnapply_kernel<<<((int)ND + 255) / 256, 256, 0, stream>>>(Out16, stats,
                                                  gamma + l * DIM, beta + l * DIM, dsq, H, H16s);
    }

    hipMemsetAsync(psums, 0, (BGRAPH * DIM + BGRAPH) * sizeof(float), stream);
    pool_kernel<<<(N_NODES + PCHUNK - 1) / PCHUNK, DIM, 0, stream>>>(H, n2g, psums, pcnts);
    mlp_kernel<<<BGRAPH, DIM, 0, stream>>>(psums, pcnts, W0, b0, W1, b1, W2, b2, (float*)d_out);
}

// Round 7
// 684.269 us; speedup vs baseline: 17.0954x; 1.2364x over previous
//
#include <hip/hip_runtime.h>

#define N_NODES 50000
#define N_EDGES 800000
#define BGRAPH  256
#define DIM     128
#define NLAYER  4
#define EPS     1e-5f
#define NPART   ((N_NODES + 255) / 256)   // 196 scan partials
#define WSZ     (384 * DIM)               // 49152 weights per layer

typedef _Float16 half8_t __attribute__((ext_vector_type(8)));
typedef float    f32x4   __attribute__((ext_vector_type(4)));

// ---------------- degree ----------------
__global__ void deg_kernel(const int* __restrict__ dst, int* __restrict__ deg) {
    int e = blockIdx.x * blockDim.x + threadIdx.x;
    if (e < N_EDGES) atomicAdd(&deg[dst[e]], 1);
}

// ---------------- hierarchical scan: deg -> row_ptr (+cursor, dsq, invd) ----------------
__global__ void scan1_kernel(const int* __restrict__ deg, int* __restrict__ part) {
    __shared__ int lds[256];
    int t = threadIdx.x;
    int i = blockIdx.x * 256 + t;
    lds[t] = (i < N_NODES) ? deg[i] : 0;
    __syncthreads();
    for (int off = 128; off > 0; off >>= 1) {
        if (t < off) lds[t] += lds[t + off];
        __syncthreads();
    }
    if (t == 0) part[blockIdx.x] = lds[0];
}

__global__ void scan2_kernel(int* __restrict__ part) {
    __shared__ int lds[256];
    int t = threadIdx.x;
    int v = (t < NPART) ? part[t] : 0;
    lds[t] = v;
    __syncthreads();
    for (int off = 1; off < 256; off <<= 1) {
        int u = (t >= off) ? lds[t - off] : 0;
        __syncthreads();
        lds[t] += u;
        __syncthreads();
    }
    if (t < NPART) part[t] = lds[t] - v;    // exclusive
}

__global__ void scan3_kernel(const int* __restrict__ deg, const int* __restrict__ part,
                             int* __restrict__ row_ptr, int* __restrict__ cursor,
                             float* __restrict__ dsq, float* __restrict__ invd) {
    __shared__ int lds[256];
    int t = threadIdx.x;
    int i = blockIdx.x * 256 + t;
    int v = (i < N_NODES) ? deg[i] : 0;
    lds[t] = v;
    __syncthreads();
    for (int off = 1; off < 256; off <<= 1) {
        int u = (t >= off) ? lds[t - off] : 0;
        __syncthreads();
        lds[t] += u;
        __syncthreads();
    }
    int excl = lds[t] - v + part[blockIdx.x];
    if (i < N_NODES) {
        row_ptr[i] = excl;
        cursor[i] = excl;
        float d = (float)(v < 1 ? 1 : v);
        dsq[i] = 1.0f / sqrtf(d);
        invd[i] = sqrtf(d);
        if (i == N_NODES - 1) row_ptr[N_NODES] = excl + v;
    }
}

__global__ void fill_kernel(const int* __restrict__ src, const int* __restrict__ dst,
                            int* __restrict__ cursor, int* __restrict__ csr_src) {
    int e = blockIdx.x * blockDim.x + threadIdx.x;
    if (e < N_EDGES) {
        int t = dst[e];
        int pos = atomicAdd(&cursor[t], 1);
        csr_src[pos] = src[e];
    }
}

// ---------------- W pack to MFMA B-fragment order ----------------
// Wpack[l][(((kb*8)+t)*64+lane)*8+j] = (f16) W[l][k=kb*32+(lane>>4)*8+j][n=t*16+(lane&15)]
__global__ void wcvt_kernel(const float* __restrict__ W, _Float16* __restrict__ Wp) {
    int idx = blockIdx.x * blockDim.x + threadIdx.x;
    if (idx >= NLAYER * WSZ) return;
    int l = idx / WSZ;
    int r = idx - l * WSZ;
    int j = r & 7, lane = (r >> 3) & 63, t = (r >> 9) & 7, kb = r >> 12;
    int k = (kb << 5) + ((lane >> 4) << 3) + j;
    int n = (t << 4) + (lane & 15);
    Wp[idx] = (_Float16)W[l * WSZ + (k << 7) + n];
}

// ---------------- atom encoder: H f32 + H16s = f16(dsq*H) ----------------
__global__ void encode_kernel(const int* __restrict__ h_idx,
                              const float* __restrict__ atom_emb,
                              const float* __restrict__ dsq,
                              float* __restrict__ H, _Float16* __restrict__ H16s) {
    int n = blockIdx.x;
    int d = threadIdx.x;
    float acc = 0.0f;
#pragma unroll
    for (int f = 0; f < 9; ++f) {
        int idx = h_idx[n * 9 + f];
        acc += atom_emb[(f * 100 + idx) * DIM + d];
    }
    H[n * DIM + d] = acc;
    H16s[n * DIM + d] = (_Float16)(acc * dsq[n]);
}

// ---------------- pull prop: 16 lanes/node, half8 (16 B) per lane ----------------
#define PGROUPS 16
__global__ void prop_kernel(const int* __restrict__ row_ptr, const int* __restrict__ csr_src,
                            const float* __restrict__ dsq,
                            const _Float16* __restrict__ Gin, const float* __restrict__ X0,
                            float alpha, float beta, _Float16* __restrict__ Gout) {
    int n = blockIdx.x * PGROUPS + (threadIdx.x >> 4);
    if (n >= N_NODES) return;
    int q = (threadIdx.x & 15) << 3;                 // f16 offset within row
    int beg = row_ptr[n], endp = row_ptr[n + 1];
    float acc[8];
#pragma unroll
    for (int j = 0; j < 8; ++j) acc[j] = 0.f;
    int i = beg;
    for (; i + 4 <= endp; i += 4) {
        int s0 = csr_src[i], s1 = csr_src[i + 1], s2 = csr_src[i + 2], s3 = csr_src[i + 3];
        half8_t r0 = *(const half8_t*)&Gin[(size_t)s0 * DIM + q];
        half8_t r1 = *(const half8_t*)&Gin[(size_t)s1 * DIM + q];
        half8_t r2 = *(const half8_t*)&Gin[(size_t)s2 * DIM + q];
        half8_t r3 = *(const half8_t*)&Gin[(size_t)s3 * DIM + q];
#pragma unroll
        for (int j = 0; j < 8; ++j)
            acc[j] += (float)r0[j] + (float)r1[j] + (float)r2[j] + (float)r3[j];
    }
    for (; i < endp; ++i) {
        int s = csr_src[i];
        half8_t r = *(const half8_t*)&Gin[(size_t)s * DIM + q];
#pragma unroll
        for (int j = 0; j < 8; ++j) acc[j] += (float)r[j];
    }
    float g = dsq[n];
    float a = alpha * g;
    half8_t out;
    if (beta != 0.0f) {
        const float* x0p = &X0[(size_t)n * DIM + q];
        float4 xa = *(const float4*)x0p;
        float4 xb = *(const float4*)(x0p + 4);
        float x0v[8] = {xa.x, xa.y, xa.z, xa.w, xb.x, xb.y, xb.z, xb.w};
#pragma unroll
        for (int j = 0; j < 8; ++j)
            out[j] = (_Float16)((a * acc[j] + beta * x0v[j]) * g);
    } else {
#pragma unroll
        for (int j = 0; j < 8; ++j)
            out[j] = (_Float16)(a * acc[j] * g);
    }
    *(half8_t*)&Gout[(size_t)n * DIM + q] = out;
}

// ---------------- MFMA GEMM v3: M=128/block, 32 rows (2 A-frags) per wave, packed-W ----------------
__global__ __launch_bounds__(256) void gemm_kernel(
        const _Float16* __restrict__ X0s, const _Float16* __restrict__ X1s,
        const _Float16* __restrict__ X2s, const float* __restrict__ invd,
        const _Float16* __restrict__ Wp,
        _Float16* __restrict__ Out16, float* __restrict__ stats) {
    const int tid  = threadIdx.x;
    const int wave = tid >> 6;
    const int lane = tid & 63;
    const int quad = lane >> 4;
    const int l15  = lane & 15;
    const int row0 = blockIdx.x * 128 + wave * 32;
    const int rA = row0 + l15;
    const int rB = row0 + 16 + l15;
    const int rAc = (rA < N_NODES) ? rA : (N_NODES - 1);
    const int rBc = (rB < N_NODES) ? rB : (N_NODES - 1);
    const _Float16 h0 = (_Float16)((rA < N_NODES) ? invd[rA] : 0.0f);
    const _Float16 h1 = (_Float16)((rB < N_NODES) ? invd[rB] : 0.0f);

    f32x4 acc0[8], acc1[8];
#pragma unroll
    for (int t = 0; t < 8; ++t) {
        acc0[t] = (f32x4){0.f, 0.f, 0.f, 0.f};
        acc1[t] = (f32x4){0.f, 0.f, 0.f, 0.f};
    }

    const _Float16* bufs[3] = {X0s, X1s, X2s};

    for (int kb = 0; kb < 12; ++kb) {
        const _Float16* Xb = bufs[kb >> 2];
        const int c0 = ((kb & 3) << 5) + (quad << 3);
        half8_t a0 = *(const half8_t*)&Xb[(size_t)rAc * DIM + c0];
        half8_t a1 = *(const half8_t*)&Xb[(size_t)rBc * DIM + c0];
#pragma unroll
        for (int j = 0; j < 8; ++j) { a0[j] = a0[j] * h0; a1[j] = a1[j] * h1; }
        const _Float16* wl = Wp + (size_t)(((kb << 3) << 6) + lane) * 8;   // (kb*8*64+lane)*8
#pragma unroll
        for (int t = 0; t < 8; ++t) {
            half8_t b = *(const half8_t*)&wl[t << 9];                      // +t*64*8
            acc0[t] = __builtin_amdgcn_mfma_f32_16x16x32_f16(a0, b, acc0[t], 0, 0, 0);
            acc1[t] = __builtin_amdgcn_mfma_f32_16x16x32_f16(a1, b, acc1[t], 0, 0, 0);
        }
    }

    // ---- store + fused BN stats (32 rows per wave) ----
    __shared__ float sred[4][DIM];
    __shared__ float s2red[4][DIM];
#pragma unroll
    for (int t = 0; t < 8; ++t) {
        const int c = (t << 4) + l15;
        float s = 0.f, s2 = 0.f;
#pragma unroll
        for (int reg = 0; reg < 4; ++reg) {
            float v0 = acc0[t][reg];
            float v1 = acc1[t][reg];
            s += v0 + v1; s2 += v0 * v0 + v1 * v1;
            int r0r = row0 + (quad << 2) + reg;
            int r1r = r0r + 16;
            if (r0r < N_NODES) Out16[(size_t)r0r * DIM + c] = (_Float16)v0;
            if (r1r < N_NODES) Out16[(size_t)r1r * DIM + c] = (_Float16)v1;
        }
        s  += __shfl_xor(s, 16);  s  += __shfl_xor(s, 32);
        s2 += __shfl_xor(s2, 16); s2 += __shfl_xor(s2, 32);
        if (quad == 0) { sred[wave][c] = s; s2red[wave][c] = s2; }
    }
    __syncthreads();
    if (tid < DIM) {
        float s = 0.f, s2 = 0.f;
#pragma unroll
        for (int w = 0; w < 4; ++w) { s += sred[w][tid]; s2 += s2red[w][tid]; }
        atomicAdd(&stats[tid], s);
        atomicAdd(&stats[DIM + tid], s2);
    }
}

// ---------------- BN apply + relu + residual; refresh H16s ----------------
__global__ void bnapply_kernel(const _Float16* __restrict__ Out16, const float* __restrict__ stats,
                               const float* __restrict__ gamma, const float* __restrict__ beta,
                               const float* __restrict__ dsq,
                               float* __restrict__ H, _Float16* __restrict__ H16s) {
    int idx = blockIdx.x * blockDim.x + threadIdx.x;
    if (idx >= N_NODES * DIM) return;
    int d = idx & 127;
    int n = idx >> 7;
    const float invN = 1.0f / (float)N_NODES;
    float mu  = stats[d] * invN;
    float var = stats[DIM + d] * invN - mu * mu;
    float sc  = (1.0f / sqrtf(var + EPS)) * gamma[d];
    float sh  = beta[d] - mu * sc;
    float v = (float)Out16[idx] * sc + sh;
    float h = H[idx] + fmaxf(v, 0.0f);
    H[idx] = h;
    H16s[idx] = (_Float16)(h * dsq[n]);
}

// ---------------- mean pool ----------------
#define PCHUNK 64
__global__ void pool_kernel(const float* __restrict__ H, const int* __restrict__ n2g,
                            float* __restrict__ sums, float* __restrict__ cnts) {
    int d = threadIdx.x;
    int r0 = blockIdx.x * PCHUNK;
    int rend = r0 + PCHUNK; if (rend > N_NODES) rend = N_NODES;
    if (r0 >= N_NODES) return;
    float acc = 0.0f;
    int cur = n2g[r0];
    int runlen = 0;
    for (int r = r0; r < rend; ++r) {
        int g = n2g[r];
        if (g != cur) {
            atomicAdd(&sums[cur * DIM + d], acc);
            if (d == 0) atomicAdd(&cnts[cur], (float)runlen);
            acc = 0.0f; runlen = 0; cur = g;
        }
        acc += H[r * DIM + d];
        runlen++;
    }
    atomicAdd(&sums[cur * DIM + d], acc);
    if (d == 0) atomicAdd(&cnts[cur], (float)runlen);
}

// ---------------- MLP readout ----------------
__global__ void mlp_kernel(const float* __restrict__ sums, const float* __restrict__ cnts,
                           const float* __restrict__ W0, const float* __restrict__ b0,
                           const float* __restrict__ W1, const float* __restrict__ b1,
                           const float* __restrict__ W2, const float* __restrict__ b2,
                           float* __restrict__ out) {
    __shared__ float hg[DIM];
    __shared__ float y0[64];
    __shared__ float y1[32];
    int g = blockIdx.x;
    int t = threadIdx.x;
    float c = cnts[g]; if (c < 1.0f) c = 1.0f;
    hg[t] = sums[g * DIM + t] / c;
    __syncthreads();
    if (t < 64) {
        float acc = b0[t];
        for (int k = 0; k < 128; ++k) acc += hg[k] * W0[k * 64 + t];
        y0[t] = fmaxf(acc, 0.0f);
    }
    __syncthreads();
    if (t < 32) {
        float acc = b1[t];
        for (int k = 0; k < 64; ++k) acc += y0[k] * W1[k * 32 + t];
        y1[t] = fmaxf(acc, 0.0f);
    }
    __syncthreads();
    {
        float acc = b2[t];
        for (int k = 0; k < 32; ++k) acc += y1[k] * W2[k * 128 + t];
        out[g * DIM + t] = acc;
    }
}

extern "C" void kernel_launch(void* const* d_in, const int* in_sizes, int n_in,
                              void* d_out, int out_size, void* d_ws, size_t ws_size,
                              hipStream_t stream) {
    const int*   h_idx = (const int*)d_in[0];
    const int*   src   = (const int*)d_in[2];
    const int*   dst   = (const int*)d_in[3];
    const int*   n2g   = (const int*)d_in[4];
    const float* atom_emb = (const float*)d_in[5];
    const float* layer_W  = (const float*)d_in[7];
    const float* gamma    = (const float*)d_in[8];
    const float* beta     = (const float*)d_in[9];
    const float* W0 = (const float*)d_in[10];
    const float* b0 = (const float*)d_in[11];
    const float* W1 = (const float*)d_in[12];
    const float* b1 = (const float*)d_in[13];
    const float* W2 = (const float*)d_in[14];
    const float* b2 = (const float*)d_in[15];

    const size_t ND = (size_t)N_NODES * DIM;

    // workspace layout (~82 MB)
    float*    H    = (float*)d_ws;                     // ND f32
    _Float16* H16s = (_Float16*)(H + ND);              // ND f16 (dsq-scaled X0)
    _Float16* A16s = H16s + ND;                        // ND f16 (dsq-scaled X1)
    _Float16* B16s = A16s + ND;                        // ND f16 (dsq-scaled X2)
    _Float16* Out16 = B16s + ND;                       // ND f16 (gemm out)
    _Float16* Wpack = Out16 + ND;                      // 4*49152 f16
    float* dsq  = (float*)(Wpack + NLAYER * WSZ);      // N
    float* invd = dsq + N_NODES;                       // N
    int*   deg  = (int*)(invd + N_NODES);              // N
    int*   row_ptr = deg + N_NODES;                    // N+1
    int*   cursor  = row_ptr + N_NODES + 1;            // N
    int*   part    = cursor + N_NODES;                 // NPART
    int*   csr_src = part + 256;                       // E
    float* stats = (float*)(csr_src + N_EDGES);        // 2*DIM
    float* psums = stats + 2 * DIM;                    // BGRAPH*DIM
    float* pcnts = psums + BGRAPH * DIM;               // BGRAPH

    // ---- CSR build + weight pack ----
    hipMemsetAsync(deg, 0, N_NODES * sizeof(int), stream);
    deg_kernel<<<(N_EDGES + 255) / 256, 256, 0, stream>>>(dst, deg);
    scan1_kernel<<<NPART, 256, 0, stream>>>(deg, part);
    scan2_kernel<<<1, 256, 0, stream>>>(part);
    scan3_kernel<<<NPART, 256, 0, stream>>>(deg, part, row_ptr, cursor, dsq, invd);
    fill_kernel<<<(N_EDGES + 255) / 256, 256, 0, stream>>>(src, dst, cursor, csr_src);
    wcvt_kernel<<<(NLAYER * WSZ + 255) / 256, 256, 0, stream>>>(layer_W, Wpack);

    encode_kernel<<<N_NODES, DIM, 0, stream>>>(h_idx, atom_emb, dsq, H, H16s);

    const int propGrid = (N_NODES + PGROUPS - 1) / PGROUPS;
    const int gemmGrid = (N_NODES + 127) / 128;
    for (int l = 0; l < NLAYER; ++l) {
        prop_kernel<<<propGrid, 256, 0, stream>>>(row_ptr, csr_src, dsq, H16s, H, -1.0f, 0.0f, A16s);
        prop_kernel<<<propGrid, 256, 0, stream>>>(row_ptr, csr_src, dsq, A16s, H, -2.0f, -1.0f, B16s);

        hipMemsetAsync(stats, 0, 2 * DIM * sizeof(float), stream);
        gemm_kernel<<<gemmGrid, 256, 0, stream>>>(H16s, A16s, B16s, invd,
                                                  Wpack + (size_t)l * WSZ, Out16, stats);

        bnapply_kernel<<<((int)ND + 255) / 256, 256, 0, stream>>>(Out16, stats,
                                                  gamma + l * DIM, beta + l * DIM, dsq, H, H16s);
    }

    hipMemsetAsync(psums, 0, (BGRAPH * DIM + BGRAPH) * sizeof(float), stream);
    pool_kernel<<<(N_NODES + PCHUNK - 1) / PCHUNK, DIM, 0, stream>>>(H, n2g, psums, pcnts);
    mlp_kernel<<<BGRAPH, DIM, 0, stream>>>(psums, pcnts, W0, b0, W1, b1, W2, b2, (float*)d_out);
}

// Round 8
// 623.176 us; speedup vs baseline: 18.7714x; 1.0980x over previous
//
#include <hip/hip_runtime.h>

#define N_NODES 50000
#define N_EDGES 800000
#define BGRAPH  256
#define DIM     128
#define NLAYER  4
#define EPS     1e-5f
#define NBUCK   ((N_NODES + 255) / 256)   // 196 buckets of 256 nodes
#define WSZ     (384 * DIM)               // 49152 weights per layer
#define EB_PER  4096                      // edges per bexpand block

typedef _Float16 half8_t __attribute__((ext_vector_type(8)));
typedef float    f32x4   __attribute__((ext_vector_type(4)));

// ---------------- CSR build v2: bucketed, write-locality-friendly ----------------
// pass 1: global bucket counts (LDS histogram, few global atomics)
__global__ __launch_bounds__(1024) void bcount_kernel(const int* __restrict__ dst,
                                                      int* __restrict__ bcnt) {
    __shared__ int h[NBUCK];
    int t = threadIdx.x;
    if (t < NBUCK) h[t] = 0;
    __syncthreads();
    for (int e = blockIdx.x * 1024 + t; e < N_EDGES; e += gridDim.x * 1024)
        atomicAdd(&h[dst[e] >> 8], 1);
    __syncthreads();
    if (t < NBUCK && h[t]) atomicAdd(&bcnt[t], h[t]);
}

// pass 2: exclusive scan of bucket counts -> boff[197], bcur copy
__global__ void bscan_kernel(const int* __restrict__ bcnt, int* __restrict__ boff,
                             int* __restrict__ bcur) {
    __shared__ int lds[256];
    int t = threadIdx.x;
    int v = (t < NBUCK) ? bcnt[t] : 0;
    lds[t] = v;
    __syncthreads();
    for (int off = 1; off < 256; off <<= 1) {
        int u = (t >= off) ? lds[t - off] : 0;
        __syncthreads();
        lds[t] += u;
        __syncthreads();
    }
    if (t < NBUCK) { int ex = lds[t] - v; boff[t] = ex; bcur[t] = ex; }
    if (t == NBUCK - 1) boff[NBUCK] = lds[t];
}

// pass 3: bin (src,dst) pairs into bucket-ordered ebuf with LDS staging + run reservation
__global__ __launch_bounds__(1024) void bexpand_kernel(const int* __restrict__ src,
                                                       const int* __restrict__ dst,
                                                       int* __restrict__ bcur,
                                                       int2* __restrict__ ebuf) {
    __shared__ int2 stage[EB_PER];       // 32 KB
    __shared__ int hist[NBUCK];
    __shared__ int lofs[NBUCK];
    __shared__ int lcur[NBUCK];
    __shared__ int gbase[NBUCK];
    __shared__ int s[256];
    int t = threadIdx.x;
    int e0 = blockIdx.x * EB_PER;
    int total = N_EDGES - e0; if (total > EB_PER) total = EB_PER;
    if (t < NBUCK) hist[t] = 0;
    __syncthreads();
    int mys[4], myd[4], myb[4];
#pragma unroll
    for (int j = 0; j < 4; ++j) {
        int e = e0 + t + j * 1024;
        if (e < N_EDGES) {
            mys[j] = src[e]; myd[j] = dst[e]; myb[j] = myd[j] >> 8;
            atomicAdd(&hist[myb[j]], 1);
        } else myb[j] = -1;
    }
    __syncthreads();
    if (t < 256) s[t] = (t < NBUCK) ? hist[t] : 0;
    __syncthreads();
    for (int off = 1; off < 256; off <<= 1) {
        int u = 0;
        if (t < 256 && t >= off) u = s[t - off];
        __syncthreads();
        if (t < 256) s[t] += u;
        __syncthreads();
    }
    if (t < NBUCK) {
        int v = hist[t];
        int ex = s[t] - v;
        lofs[t] = ex; lcur[t] = ex;
        gbase[t] = (v > 0) ? atomicAdd(&bcur[t], v) : 0;
    }
    __syncthreads();
#pragma unroll
    for (int j = 0; j < 4; ++j) if (myb[j] >= 0) {
        int p = atomicAdd(&lcur[myb[j]], 1);
        stage[p] = make_int2(mys[j], myd[j]);
    }
    __syncthreads();
    for (int i = t; i < total; i += 1024) {
        int2 p = stage[i];
        int bu = p.y >> 8;
        ebuf[gbase[bu] + (i - lofs[bu])] = p;
    }
}

// pass 4: per-bucket CSR finalize: row_ptr, dsq, invd, csr_src (single-XCD-local writes)
__global__ __launch_bounds__(256) void bbuild_kernel(const int2* __restrict__ ebuf,
                                                     const int* __restrict__ boff,
                                                     int* __restrict__ row_ptr,
                                                     float* __restrict__ dsq,
                                                     float* __restrict__ invd,
                                                     int* __restrict__ csr_src) {
    __shared__ int hist[256];
    __shared__ int s[256];
    __shared__ int lcur[256];
    int b = blockIdx.x, t = threadIdx.x;
    int base = boff[b], cnt = boff[b + 1] - base;
    int node0 = b << 8;
    hist[t] = 0;
    __syncthreads();
    for (int i = t; i < cnt; i += 256)
        atomicAdd(&hist[ebuf[base + i].y & 255], 1);
    __syncthreads();
    int v = hist[t];
    s[t] = v;
    __syncthreads();
    for (int off = 1; off < 256; off <<= 1) {
        int u = (t >= off) ? s[t - off] : 0;
        __syncthreads();
        s[t] += u;
        __syncthreads();
    }
    int excl = s[t] - v;
    lcur[t] = excl;
    int n = node0 + t;
    if (n < N_NODES) {
        row_ptr[n] = base + excl;
        float d = (float)(v < 1 ? 1 : v);
        dsq[n] = 1.0f / sqrtf(d);
        invd[n] = sqrtf(d);
        if (n == N_NODES - 1) row_ptr[N_NODES] = base + excl + v;   // = E
    }
    __syncthreads();
    for (int i = t; i < cnt; i += 256) {
        int2 p = ebuf[base + i];
        int slot = atomicAdd(&lcur[p.y & 255], 1);
        csr_src[base + slot] = p.x;
    }
}

// ---------------- W pack to MFMA B-fragment order ----------------
__global__ void wcvt_kernel(const float* __restrict__ W, _Float16* __restrict__ Wp) {
    int idx = blockIdx.x * blockDim.x + threadIdx.x;
    if (idx >= NLAYER * WSZ) return;
    int l = idx / WSZ;
    int r = idx - l * WSZ;
    int j = r & 7, lane = (r >> 3) & 63, t = (r >> 9) & 7, kb = r >> 12;
    int k = (kb << 5) + ((lane >> 4) << 3) + j;
    int n = (t << 4) + (lane & 15);
    Wp[idx] = (_Float16)W[l * WSZ + (k << 7) + n];
}

// ---------------- atom encoder: H f32 + H16s = f16(dsq*H) ----------------
__global__ void encode_kernel(const int* __restrict__ h_idx,
                              const float* __restrict__ atom_emb,
                              const float* __restrict__ dsq,
                              float* __restrict__ H, _Float16* __restrict__ H16s) {
    int n = blockIdx.x;
    int d = threadIdx.x;
    float acc = 0.0f;
#pragma unroll
    for (int f = 0; f < 9; ++f) {
        int idx = h_idx[n * 9 + f];
        acc += atom_emb[(f * 100 + idx) * DIM + d];
    }
    H[n * DIM + d] = acc;
    H16s[n * DIM + d] = (_Float16)(acc * dsq[n]);
}

// ---------------- pull prop: 16 lanes/node, double-buffered 4-row batches (8 loads in flight) ----
#define PGROUPS 16
#define ACC8(r) { _Pragma("unroll") for (int j = 0; j < 8; ++j) acc[j] += (float)(r)[j]; }
__global__ void prop_kernel(const int* __restrict__ row_ptr, const int* __restrict__ csr_src,
                            const float* __restrict__ dsq,
                            const _Float16* __restrict__ Gin, const float* __restrict__ X0,
                            float alpha, float beta, _Float16* __restrict__ Gout) {
    int n = blockIdx.x * PGROUPS + (threadIdx.x >> 4);
    if (n >= N_NODES) return;
    int q = (threadIdx.x & 15) << 3;
    int beg = row_ptr[n], endp = row_ptr[n + 1];
    float acc[8];
#pragma unroll
    for (int j = 0; j < 8; ++j) acc[j] = 0.f;
    int i = beg;
    if (i + 8 <= endp) {
        int s0 = csr_src[i], s1 = csr_src[i+1], s2 = csr_src[i+2], s3 = csr_src[i+3];
        half8_t a0 = *(const half8_t*)&Gin[(size_t)s0 * DIM + q];
        half8_t a1 = *(const half8_t*)&Gin[(size_t)s1 * DIM + q];
        half8_t a2 = *(const half8_t*)&Gin[(size_t)s2 * DIM + q];
        half8_t a3 = *(const half8_t*)&Gin[(size_t)s3 * DIM + q];
        i += 4;
        for (; i + 4 <= endp; i += 4) {
            int t0 = csr_src[i], t1 = csr_src[i+1], t2 = csr_src[i+2], t3 = csr_src[i+3];
            half8_t b0 = *(const half8_t*)&Gin[(size_t)t0 * DIM + q];
            half8_t b1 = *(const half8_t*)&Gin[(size_t)t1 * DIM + q];
            half8_t b2 = *(const half8_t*)&Gin[(size_t)t2 * DIM + q];
            half8_t b3 = *(const half8_t*)&Gin[(size_t)t3 * DIM + q];
            ACC8(a0); ACC8(a1); ACC8(a2); ACC8(a3);
            a0 = b0; a1 = b1; a2 = b2; a3 = b3;
        }
        ACC8(a0); ACC8(a1); ACC8(a2); ACC8(a3);
    }
    for (; i + 4 <= endp; i += 4) {
        int s0 = csr_src[i], s1 = csr_src[i+1], s2 = csr_src[i+2], s3 = csr_src[i+3];
        half8_t r0 = *(const half8_t*)&Gin[(size_t)s0 * DIM + q];
        half8_t r1 = *(const half8_t*)&Gin[(size_t)s1 * DIM + q];
        half8_t r2 = *(const half8_t*)&Gin[(size_t)s2 * DIM + q];
        half8_t r3 = *(const half8_t*)&Gin[(size_t)s3 * DIM + q];
        ACC8(r0); ACC8(r1); ACC8(r2); ACC8(r3);
    }
    for (; i < endp; ++i) {
        int s = csr_src[i];
        half8_t r = *(const half8_t*)&Gin[(size_t)s * DIM + q];
        ACC8(r);
    }
    float g = dsq[n];
    float a = alpha * g;
    half8_t out;
    if (beta != 0.0f) {
        const float* x0p = &X0[(size_t)n * DIM + q];
        float4 xa = *(const float4*)x0p;
        float4 xb = *(const float4*)(x0p + 4);
        float x0v[8] = {xa.x, xa.y, xa.z, xa.w, xb.x, xb.y, xb.z, xb.w};
#pragma unroll
        for (int j = 0; j < 8; ++j)
            out[j] = (_Float16)((a * acc[j] + beta * x0v[j]) * g);
    } else {
#pragma unroll
        for (int j = 0; j < 8; ++j)
            out[j] = (_Float16)(a * acc[j] * g);
    }
    *(half8_t*)&Gout[(size_t)n * DIM + q] = out;
}

// ---------------- MFMA GEMM: M=128/block, 32 rows (2 A-frags) per wave, packed-W ----------------
__global__ __launch_bounds__(256) void gemm_kernel(
        const _Float16* __restrict__ X0s, const _Float16* __restrict__ X1s,
        const _Float16* __restrict__ X2s, const float* __restrict__ invd,
        const _Float16* __restrict__ Wp,
        _Float16* __restrict__ Out16, float* __restrict__ stats) {
    const int tid  = threadIdx.x;
    const int wave = tid >> 6;
    const int lane = tid & 63;
    const int quad = lane >> 4;
    const int l15  = lane & 15;
    const int row0 = blockIdx.x * 128 + wave * 32;
    const int rA = row0 + l15;
    const int rB = row0 + 16 + l15;
    const int rAc = (rA < N_NODES) ? rA : (N_NODES - 1);
    const int rBc = (rB < N_NODES) ? rB : (N_NODES - 1);
    const _Float16 h0 = (_Float16)((rA < N_NODES) ? invd[rA] : 0.0f);
    const _Float16 h1 = (_Float16)((rB < N_NODES) ? invd[rB] : 0.0f);

    f32x4 acc0[8], acc1[8];
#pragma unroll
    for (int t = 0; t < 8; ++t) {
        acc0[t] = (f32x4){0.f, 0.f, 0.f, 0.f};
        acc1[t] = (f32x4){0.f, 0.f, 0.f, 0.f};
    }

    const _Float16* bufs[3] = {X0s, X1s, X2s};

    for (int kb = 0; kb < 12; ++kb) {
        const _Float16* Xb = bufs[kb >> 2];
        const int c0 = ((kb & 3) << 5) + (quad << 3);
        half8_t a0 = *(const half8_t*)&Xb[(size_t)rAc * DIM + c0];
        half8_t a1 = *(const half8_t*)&Xb[(size_t)rBc * DIM + c0];
#pragma unroll
        for (int j = 0; j < 8; ++j) { a0[j] = a0[j] * h0; a1[j] = a1[j] * h1; }
        const _Float16* wl = Wp + (size_t)(((kb << 3) << 6) + lane) * 8;
#pragma unroll
        for (int t = 0; t < 8; ++t) {
            half8_t b = *(const half8_t*)&wl[t << 9];
            acc0[t] = __builtin_amdgcn_mfma_f32_16x16x32_f16(a0, b, acc0[t], 0, 0, 0);
            acc1[t] = __builtin_amdgcn_mfma_f32_16x16x32_f16(a1, b, acc1[t], 0, 0, 0);
        }
    }

    __shared__ float sred[4][DIM];
    __shared__ float s2red[4][DIM];
#pragma unroll
    for (int t = 0; t < 8; ++t) {
        const int c = (t << 4) + l15;
        float s = 0.f, s2 = 0.f;
#pragma unroll
        for (int reg = 0; reg < 4; ++reg) {
            float v0 = acc0[t][reg];
            float v1 = acc1[t][reg];
            s += v0 + v1; s2 += v0 * v0 + v1 * v1;
            int r0r = row0 + (quad << 2) + reg;
            int r1r = r0r + 16;
            if (r0r < N_NODES) Out16[(size_t)r0r * DIM + c] = (_Float16)v0;
            if (r1r < N_NODES) Out16[(size_t)r1r * DIM + c] = (_Float16)v1;
        }
        s  += __shfl_xor(s, 16);  s  += __shfl_xor(s, 32);
        s2 += __shfl_xor(s2, 16); s2 += __shfl_xor(s2, 32);
        if (quad == 0) { sred[wave][c] = s; s2red[wave][c] = s2; }
    }
    __syncthreads();
    if (tid < DIM) {
        float s = 0.f, s2 = 0.f;
#pragma unroll
        for (int w = 0; w < 4; ++w) { s += sred[w][tid]; s2 += s2red[w][tid]; }
        atomicAdd(&stats[tid], s);
        atomicAdd(&stats[DIM + tid], s2);
    }
}

// ---------------- BN apply + relu + residual; refresh H16s ----------------
__global__ void bnapply_kernel(const _Float16* __restrict__ Out16, const float* __restrict__ stats,
                               const float* __restrict__ gamma, const float* __restrict__ beta,
                               const float* __restrict__ dsq,
                               float* __restrict__ H, _Float16* __restrict__ H16s) {
    int idx = blockIdx.x * blockDim.x + threadIdx.x;
    if (idx >= N_NODES * DIM) return;
    int d = idx & 127;
    int n = idx >> 7;
    const float invN = 1.0f / (float)N_NODES;
    float mu  = stats[d] * invN;
    float var = stats[DIM + d] * invN - mu * mu;
    float sc  = (1.0f / sqrtf(var + EPS)) * gamma[d];
    float sh  = beta[d] - mu * sc;
    float v = (float)Out16[idx] * sc + sh;
    float h = H[idx] + fmaxf(v, 0.0f);
    H[idx] = h;
    H16s[idx] = (_Float16)(h * dsq[n]);
}

// ---------------- mean pool ----------------
#define PCHUNK 64
__global__ void pool_kernel(const float* __restrict__ H, const int* __restrict__ n2g,
                            float* __restrict__ sums, float* __restrict__ cnts) {
    int d = threadIdx.x;
    int r0 = blockIdx.x * PCHUNK;
    int rend = r0 + PCHUNK; if (rend > N_NODES) rend = N_NODES;
    if (r0 >= N_NODES) return;
    float acc = 0.0f;
    int cur = n2g[r0];
    int runlen = 0;
    for (int r = r0; r < rend; ++r) {
        int g = n2g[r];
        if (g != cur) {
            atomicAdd(&sums[cur * DIM + d], acc);
            if (d == 0) atomicAdd(&cnts[cur], (float)runlen);
            acc = 0.0f; runlen = 0; cur = g;
        }
        acc += H[r * DIM + d];
        runlen++;
    }
    atomicAdd(&sums[cur * DIM + d], acc);
    if (d == 0) atomicAdd(&cnts[cur], (float)runlen);
}

// ---------------- MLP readout ----------------
__global__ void mlp_kernel(const float* __restrict__ sums, const float* __restrict__ cnts,
                           const float* __restrict__ W0, const float* __restrict__ b0,
                           const float* __restrict__ W1, const float* __restrict__ b1,
                           const float* __restrict__ W2, const float* __restrict__ b2,
                           float* __restrict__ out) {
    __shared__ float hg[DIM];
    __shared__ float y0[64];
    __shared__ float y1[32];
    int g = blockIdx.x;
    int t = threadIdx.x;
    float c = cnts[g]; if (c < 1.0f) c = 1.0f;
    hg[t] = sums[g * DIM + t] / c;
    __syncthreads();
    if (t < 64) {
        float acc = b0[t];
        for (int k = 0; k < 128; ++k) acc += hg[k] * W0[k * 64 + t];
        y0[t] = fmaxf(acc, 0.0f);
    }
    __syncthreads();
    if (t < 32) {
        float acc = b1[t];
        for (int k = 0; k < 64; ++k) acc += y0[k] * W1[k * 32 + t];
        y1[t] = fmaxf(acc, 0.0f);
    }
    __syncthreads();
    {
        float acc = b2[t];
        for (int k = 0; k < 32; ++k) acc += y1[k] * W2[k * 128 + t];
        out[g * DIM + t] = acc;
    }
}

extern "C" void kernel_launch(void* const* d_in, const int* in_sizes, int n_in,
                              void* d_out, int out_size, void* d_ws, size_t ws_size,
                              hipStream_t stream) {
    const int*   h_idx = (const int*)d_in[0];
    const int*   src   = (const int*)d_in[2];
    const int*   dst   = (const int*)d_in[3];
    const int*   n2g   = (const int*)d_in[4];
    const float* atom_emb = (const float*)d_in[5];
    const float* layer_W  = (const float*)d_in[7];
    const float* gamma    = (const float*)d_in[8];
    const float* beta     = (const float*)d_in[9];
    const float* W0 = (const float*)d_in[10];
    const float* b0 = (const float*)d_in[11];
    const float* W1 = (const float*)d_in[12];
    const float* b1 = (const float*)d_in[13];
    const float* W2 = (const float*)d_in[14];
    const float* b2 = (const float*)d_in[15];

    const size_t ND = (size_t)N_NODES * DIM;

    // workspace layout (~76 MB)
    float*    H    = (float*)d_ws;                     // ND f32
    _Float16* H16s = (_Float16*)(H + ND);              // ND f16 (dsq-scaled X0)
    _Float16* A16s = H16s + ND;                        // ND f16 (dsq-scaled X1)
    _Float16* B16s = A16s + ND;                        // ND f16 (dsq-scaled X2)
    _Float16* Out16 = B16s + ND;                       // ND f16 (gemm out)
    int2*     ebuf  = (int2*)Out16;                    // E int2 — aliases Out16 (dead until gemm)
    _Float16* Wpack = Out16 + ND;                      // 4*49152 f16
    float* dsq  = (float*)(Wpack + NLAYER * WSZ);      // N
    float* invd = dsq + N_NODES;                       // N
    int*   row_ptr = (int*)(invd + N_NODES);           // N+1
    int*   csr_src = row_ptr + N_NODES + 1;            // E
    int*   bcnt = csr_src + N_EDGES;                   // NBUCK
    int*   boff = bcnt + NBUCK;                        // NBUCK+1
    int*   bcur = boff + NBUCK + 1;                    // NBUCK
    float* stats = (float*)(bcur + NBUCK);             // 2*DIM
    float* psums = stats + 2 * DIM;                    // BGRAPH*DIM
    float* pcnts = psums + BGRAPH * DIM;               // BGRAPH

    // ---- CSR build v2 ----
    hipMemsetAsync(bcnt, 0, NBUCK * sizeof(int), stream);
    bcount_kernel<<<128, 1024, 0, stream>>>(dst, bcnt);
    bscan_kernel<<<1, 256, 0, stream>>>(bcnt, boff, bcur);
    bexpand_kernel<<<(N_EDGES + EB_PER - 1) / EB_PER, 1024, 0, stream>>>(src, dst, bcur, ebuf);
    bbuild_kernel<<<NBUCK, 256, 0, stream>>>(ebuf, boff, row_ptr, dsq, invd, csr_src);
    wcvt_kernel<<<(NLAYER * WSZ + 255) / 256, 256, 0, stream>>>(layer_W, Wpack);

    encode_kernel<<<N_NODES, DIM, 0, stream>>>(h_idx, atom_emb, dsq, H, H16s);

    const int propGrid = (N_NODES + PGROUPS - 1) / PGROUPS;
    const int gemmGrid = (N_NODES + 127) / 128;
    for (int l = 0; l < NLAYER; ++l) {
        prop_kernel<<<propGrid, 256, 0, stream>>>(row_ptr, csr_src, dsq, H16s, H, -1.0f, 0.0f, A16s);
        prop_kernel<<<propGrid, 256, 0, stream>>>(row_ptr, csr_src, dsq, A16s, H, -2.0f, -1.0f, B16s);

        hipMemsetAsync(stats, 0, 2 * DIM * sizeof(float), stream);
        gemm_kernel<<<gemmGrid, 256, 0, stream>>>(H16s, A16s, B16s, invd,
                                                  Wpack + (size_t)l * WSZ, Out16, stats);

        bnapply_kernel<<<((int)ND + 255) / 256, 256, 0, stream>>>(Out16, stats,
                                                  gamma + l * DIM, beta + l * DIM, dsq, H, H16s);
    }

    hipMemsetAsync(psums, 0, (BGRAPH * DIM + BGRAPH) * sizeof(float), stream);
    pool_kernel<<<(N_NODES + PCHUNK - 1) / PCHUNK, DIM, 0, stream>>>(H, n2g, psums, pcnts);
    mlp_kernel<<<BGRAPH, DIM, 0, stream>>>(psums, pcnts, W0, b0, W1, b1, W2, b2, (float*)d_out);
}